// Round 10
// baseline (478.906 us; speedup 1.0000x reference)
//
#include <hip/hip_runtime.h>
#include <hip/hip_fp16.h>

// EMD approx-match (auction) + match_cost, fused so the [B,N,M] match matrix
// is never materialized. O(B*N) state in d_ws: remainL, remainR, rowscale,
// colcoef. 20 kernels: A0, {B(l), CA(l)} l=0..8, C9 (B9's t1 + colcoef fold
// done per-block in C9 staging).
//
// R10 = R6 PROVEN kernel verbatim (AoS float4 LDS staging, scalar fast exp2 /
// sqrt) + ONE delta: B9 folded into C9. R7-R9 post-mortem: the SoA/v2f-cast
// LDS rewrite fails structurally (absmax 284-316, insensitive to three
// different exp impls) -- v2f casts of float LDS arrays are abandoned.
// Dot-form d2 rejected: catastrophic cancellation for near pairs (rel err
// ~6e-3 on d2~1e-4 -> ~1% exp err, worse than R7's 8e-4 that failed).

#define BATCH 8
#define NPTS 2048
#define MPTS 2048
#define BLOCK 256
#define ROWS 16
#define LOG2E 1.44269504088896340736f

// Pure-VALU 2^x. x <= 0 here; ldexp handles underflow -> 0. ~4e-5 rel.
__device__ __forceinline__ float fast_exp2(float x) {
  float rn = __builtin_rintf(x);        // v_rndne_f32
  float g = x - rn;                     // g in [-0.5, 0.5]
  float p = __builtin_fmaf(
      g,
      __builtin_fmaf(
          g,
          __builtin_fmaf(g,
                         __builtin_fmaf(g, 0.009618129107628477f,
                                        0.05550410866482158f),
                         0.2402265069591007f),
          0.6931471805599453f),
      1.0f);
  return ldexpf(p, (int)rn);            // v_cvt_i32 + v_ldexp_f32
}

// Pure-VALU sqrt(a), a >= 0. Bit-hack rsqrt seed + 2 Newton; a=0 -> 0. ~1e-5.
__device__ __forceinline__ float fast_sqrt(float a) {
  int i = 0x5f3759df - (__builtin_bit_cast(int, a) >> 1);
  float y = __builtin_bit_cast(float, i);
  float h = 0.5f * a;
  y = y * __builtin_fmaf(-h * y, y, 1.5f);
  y = y * __builtin_fmaf(-h * y, y, 1.5f);
  return a * y;
}

// ---------------------------------------------------------------------------
// A0: rowscale[b,n] = 1/(sum_m exp(lvl0*d2) + 1e-9). Also zeroes out[].
__global__ __launch_bounds__(BLOCK, 4) void emd_A0_kernel(
    const float* __restrict__ xyz1, const float* __restrict__ xyz2,
    float* __restrict__ rowscale, float* __restrict__ out) {
  __shared__ float4 sP[MPTS];
  __shared__ float sRed[ROWS * 4];

  const int tid = threadIdx.x;
  const int bid = blockIdx.x;
  const int b = bid >> 7;
  const int t0 = (bid & 127) * ROWS;
  if (bid == 0 && tid < BATCH) out[tid] = 0.0f;

  for (int m = tid; m < MPTS; m += BLOCK) {
    const float* p = xyz2 + ((size_t)b * MPTS + m) * 3;
    sP[m] = make_float4(p[0], p[1], p[2], 0.0f);
  }
  __syncthreads();

  const int wave = tid >> 6, lane = tid & 63;
  const int phase = lane >> 1, rg = lane & 1;
  const int r0 = t0 + rg * 8;
  const float L2 = -16384.0f * LOG2E;
  float x1[8], y1[8], z1[8], acc[8];
#pragma unroll
  for (int j = 0; j < 8; ++j) {
    const float* p = xyz1 + ((size_t)b * NPTS + r0 + j) * 3;
    x1[j] = p[0]; y1[j] = p[1]; z1[j] = p[2]; acc[j] = 0.0f;
  }
  const int mb = wave * 512 + phase;
#pragma unroll 4
  for (int it = 0; it < 16; ++it) {
    float4 v = sP[mb + it * 32];
#pragma unroll
    for (int j = 0; j < 8; ++j) {
      float dx = x1[j] - v.x, dy = y1[j] - v.y, dz = z1[j] - v.z;
      float d2 = __builtin_fmaf(dx, dx, __builtin_fmaf(dy, dy, dz * dz));
      acc[j] += fast_exp2(L2 * d2);
    }
  }
#pragma unroll
  for (int j = 0; j < 8; ++j) {
    acc[j] += __shfl_xor(acc[j], 2, 64);
    acc[j] += __shfl_xor(acc[j], 4, 64);
    acc[j] += __shfl_xor(acc[j], 8, 64);
    acc[j] += __shfl_xor(acc[j], 16, 64);
    acc[j] += __shfl_xor(acc[j], 32, 64);
  }
  if (lane < 2) {
#pragma unroll
    for (int j = 0; j < 8; ++j) sRed[(rg * 8 + j) * 4 + wave] = acc[j];
  }
  __syncthreads();
  if (tid < ROWS) {
    float s = sRed[tid * 4] + sRed[tid * 4 + 1] + sRed[tid * 4 + 2] +
              sRed[tid * 4 + 3];
    rowscale[(size_t)b * NPTS + t0 + tid] = 1.0f / (s + 1e-9f);
  }
}

// ---------------------------------------------------------------------------
// B(l): col pass. t1 = sum_n exp(lvl*d2)*rs[n]; colsum = rr*t1;
// cs = min(rr/(colsum+1e-9),1); colcoef = rr*cs; remainR = max(rr-colsum*cs,0)
template <bool FIRST>
__global__ __launch_bounds__(BLOCK, 4) void emd_B_kernel(
    const float* __restrict__ xyz1, const float* __restrict__ xyz2,
    const float* __restrict__ rowscale, float* __restrict__ remainR,
    float* __restrict__ colcoef, float L2C) {
  __shared__ float4 sP[NPTS];   // (x1,y1,z1, rowscale)
  __shared__ float sRed[ROWS * 4];

  const int tid = threadIdx.x;
  const int bid = blockIdx.x;
  const int b = bid >> 7;
  const int t0 = (bid & 127) * ROWS;

  for (int n = tid; n < NPTS; n += BLOCK) {
    const float* p = xyz1 + ((size_t)b * NPTS + n) * 3;
    sP[n] = make_float4(p[0], p[1], p[2], rowscale[b * NPTS + n]);
  }
  __syncthreads();

  const int wave = tid >> 6, lane = tid & 63;
  const int phase = lane >> 1, rg = lane & 1;
  const int c0 = t0 + rg * 8;
  float x2[8], y2[8], z2[8], acc[8];
#pragma unroll
  for (int j = 0; j < 8; ++j) {
    const float* p = xyz2 + ((size_t)b * MPTS + c0 + j) * 3;
    x2[j] = p[0]; y2[j] = p[1]; z2[j] = p[2]; acc[j] = 0.0f;
  }
  const int nb = wave * 512 + phase;
#pragma unroll 4
  for (int it = 0; it < 16; ++it) {
    float4 v = sP[nb + it * 32];
#pragma unroll
    for (int j = 0; j < 8; ++j) {
      float dx = x2[j] - v.x, dy = y2[j] - v.y, dz = z2[j] - v.z;
      float d2 = __builtin_fmaf(dx, dx, __builtin_fmaf(dy, dy, dz * dz));
      acc[j] = __builtin_fmaf(fast_exp2(L2C * d2), v.w, acc[j]);
    }
  }
#pragma unroll
  for (int j = 0; j < 8; ++j) {
    acc[j] += __shfl_xor(acc[j], 2, 64);
    acc[j] += __shfl_xor(acc[j], 4, 64);
    acc[j] += __shfl_xor(acc[j], 8, 64);
    acc[j] += __shfl_xor(acc[j], 16, 64);
    acc[j] += __shfl_xor(acc[j], 32, 64);
  }
  if (lane < 2) {
#pragma unroll
    for (int j = 0; j < 8; ++j) sRed[(rg * 8 + j) * 4 + wave] = acc[j];
  }
  __syncthreads();
  if (tid < ROWS) {
    float t1 = sRed[tid * 4] + sRed[tid * 4 + 1] + sRed[tid * 4 + 2] +
               sRed[tid * 4 + 3];
    size_t idx = (size_t)b * MPTS + t0 + tid;
    float rr = FIRST ? 1.0f : remainR[idx];
    float colsum = rr * t1;
    float cs = fminf(rr / (colsum + 1e-9f), 1.0f);
    colcoef[idx] = rr * cs;
    remainR[idx] = fmaxf(rr - colsum * cs, 0.0f);
  }
}

// ---------------------------------------------------------------------------
// CA(l): row pass: cost(l) + remainL update + rowscale(l+1).
// e2 = exp(lvl/4*d2) (ONE exp); e1 = e2^4 = exp(lvl*d2).
// LAST (l==8): next lvl = 0 -> e2 = 1, e1 = exp2(L2C*d2) directly.
template <bool FIRST, bool LAST>
__global__ __launch_bounds__(BLOCK, 4) void emd_CA_kernel(
    const float* __restrict__ xyz1, const float* __restrict__ xyz2,
    float* __restrict__ rowscale, float* __restrict__ remainL,
    const float* __restrict__ remainR, const float* __restrict__ colcoef,
    float* __restrict__ out, float L2C, float L2A) {
  __shared__ float4 sP[MPTS];   // (x2,y2,z2, half2(cc, rr))
  __shared__ float sRedS[ROWS * 4];
  __shared__ float sRedC[ROWS * 4];
  __shared__ float sRedR[ROWS * 4];
  __shared__ float sCost[ROWS];

  const int tid = threadIdx.x;
  const int bid = blockIdx.x;
  const int b = bid >> 7;
  const int t0 = (bid & 127) * ROWS;

  for (int m = tid; m < MPTS; m += BLOCK) {
    size_t idx = (size_t)b * MPTS + m;
    const float* p = xyz2 + idx * 3;
    __half2 h = __halves2half2(__float2half_rn(colcoef[idx]),
                               __float2half_rn(remainR[idx]));
    sP[m] = make_float4(p[0], p[1], p[2], __builtin_bit_cast(float, h));
  }
  __syncthreads();

  const int wave = tid >> 6, lane = tid & 63;
  const int phase = lane >> 2, rg = lane & 3;
  const int r0 = t0 + rg * 4;
  float x1[4], y1[4], z1[4];
#pragma unroll
  for (int j = 0; j < 4; ++j) {
    const float* p = xyz1 + ((size_t)b * NPTS + r0 + j) * 3;
    x1[j] = p[0]; y1[j] = p[1]; z1[j] = p[2];
  }
  float accS[4] = {0.f, 0.f, 0.f, 0.f};
  float accC[4] = {0.f, 0.f, 0.f, 0.f};
  float accR[4] = {0.f, 0.f, 0.f, 0.f};
  const int mb = wave * 512 + phase;
#pragma unroll 4
  for (int it = 0; it < 32; ++it) {
    float4 v = sP[mb + it * 16];
    __half2 h = __builtin_bit_cast(__half2, v.w);
    float cc = __low2float(h);
    float rr = __high2float(h);
#pragma unroll
    for (int j = 0; j < 4; ++j) {
      float dx = x1[j] - v.x, dy = y1[j] - v.y, dz = z1[j] - v.z;
      float d2 = __builtin_fmaf(dx, dx, __builtin_fmaf(dy, dy, dz * dz));
      float sq = fast_sqrt(d2);
      float e1, e2;
      if (LAST) {
        e2 = 1.0f;
        e1 = fast_exp2(L2C * d2);
      } else {
        e2 = fast_exp2(L2A * d2);
        float e2s = e2 * e2;
        e1 = e2s * e2s;             // exp(4*lvlA*d2) exactly matches lvlC
      }
      float t = e1 * cc;
      accS[j] += t;
      accC[j] = __builtin_fmaf(t, sq, accC[j]);
      accR[j] = __builtin_fmaf(e2, rr, accR[j]);
    }
  }
#pragma unroll
  for (int j = 0; j < 4; ++j) {
    accS[j] += __shfl_xor(accS[j], 4, 64);
    accS[j] += __shfl_xor(accS[j], 8, 64);
    accS[j] += __shfl_xor(accS[j], 16, 64);
    accS[j] += __shfl_xor(accS[j], 32, 64);
    accC[j] += __shfl_xor(accC[j], 4, 64);
    accC[j] += __shfl_xor(accC[j], 8, 64);
    accC[j] += __shfl_xor(accC[j], 16, 64);
    accC[j] += __shfl_xor(accC[j], 32, 64);
    accR[j] += __shfl_xor(accR[j], 4, 64);
    accR[j] += __shfl_xor(accR[j], 8, 64);
    accR[j] += __shfl_xor(accR[j], 16, 64);
    accR[j] += __shfl_xor(accR[j], 32, 64);
  }
  if (lane < 4) {
#pragma unroll
    for (int j = 0; j < 4; ++j) {
      sRedS[(rg * 4 + j) * 4 + wave] = accS[j];
      sRedC[(rg * 4 + j) * 4 + wave] = accC[j];
      sRedR[(rg * 4 + j) * 4 + wave] = accR[j];
    }
  }
  __syncthreads();
  if (tid < ROWS) {
    float S2 = sRedS[tid * 4] + sRedS[tid * 4 + 1] + sRedS[tid * 4 + 2] +
               sRedS[tid * 4 + 3];
    float C = sRedC[tid * 4] + sRedC[tid * 4 + 1] + sRedC[tid * 4 + 2] +
              sRedC[tid * 4 + 3];
    float R = sRedR[tid * 4] + sRedR[tid * 4 + 1] + sRedR[tid * 4 + 2] +
              sRedR[tid * 4 + 3];
    size_t idx = (size_t)b * NPTS + t0 + tid;
    float rs = rowscale[idx];
    float rl = FIRST ? 1.0f : remainL[idx];
    float rlN = fmaxf(rl - rs * S2, 0.0f);
    remainL[idx] = rlN;
    rowscale[idx] = rlN / (R + 1e-9f);  // next level's rowscale
    sCost[tid] = rs * C;
  }
  __syncthreads();
  if (tid == 0) {
    float t = 0.0f;
#pragma unroll
    for (int i = 0; i < ROWS; ++i) t += sCost[i];
    atomicAdd(out + b, t);
  }
}

// ---------------------------------------------------------------------------
// C9 (lvl=0), with B9 folded in: t1 = sum_n rs[n] (block-local reduction,
// same order as the old B9 kernel); colcoef computed during staging;
// cost[b] += rs[n] * sum_m cc[m]*sqrt(d2).
__global__ __launch_bounds__(BLOCK, 4) void emd_C9_kernel(
    const float* __restrict__ xyz1, const float* __restrict__ xyz2,
    const float* __restrict__ rowscale, const float* __restrict__ remainR,
    float* __restrict__ out) {
  __shared__ float4 sP[MPTS];   // (x2,y2,z2, colcoef)
  __shared__ float sRed[ROWS * 4];
  __shared__ float sCost[ROWS];
  __shared__ float sT[4];

  const int tid = threadIdx.x;
  const int bid = blockIdx.x;
  const int b = bid >> 7;
  const int t0 = (bid & 127) * ROWS;
  const int wave = tid >> 6, lane = tid & 63;

  // t1 = sum_n rowscale[b,n] (former B9 reduction, identical order)
  float s = 0.0f;
#pragma unroll
  for (int k = 0; k < NPTS / BLOCK; ++k)
    s += rowscale[(size_t)b * NPTS + tid + k * BLOCK];
  s += __shfl_xor(s, 1, 64);  s += __shfl_xor(s, 2, 64);
  s += __shfl_xor(s, 4, 64);  s += __shfl_xor(s, 8, 64);
  s += __shfl_xor(s, 16, 64); s += __shfl_xor(s, 32, 64);
  if (lane == 0) sT[wave] = s;
  __syncthreads();
  const float t1 = sT[0] + sT[1] + sT[2] + sT[3];

  for (int m = tid; m < MPTS; m += BLOCK) {
    size_t idx = (size_t)b * MPTS + m;
    const float* p = xyz2 + idx * 3;
    float rr = remainR[idx];
    float colsum = rr * t1;
    float cs = fminf(rr / (colsum + 1e-9f), 1.0f);
    sP[m] = make_float4(p[0], p[1], p[2], rr * cs);
  }
  __syncthreads();

  const int phase = lane >> 1, rg = lane & 1;
  const int r0 = t0 + rg * 8;
  float x1[8], y1[8], z1[8], acc[8];
#pragma unroll
  for (int j = 0; j < 8; ++j) {
    const float* p = xyz1 + ((size_t)b * NPTS + r0 + j) * 3;
    x1[j] = p[0]; y1[j] = p[1]; z1[j] = p[2]; acc[j] = 0.0f;
  }
  const int mb = wave * 512 + phase;
#pragma unroll 4
  for (int it = 0; it < 16; ++it) {
    float4 v = sP[mb + it * 32];
#pragma unroll
    for (int j = 0; j < 8; ++j) {
      float dx = x1[j] - v.x, dy = y1[j] - v.y, dz = z1[j] - v.z;
      float d2 = __builtin_fmaf(dx, dx, __builtin_fmaf(dy, dy, dz * dz));
      acc[j] = __builtin_fmaf(fast_sqrt(d2), v.w, acc[j]);
    }
  }
#pragma unroll
  for (int j = 0; j < 8; ++j) {
    acc[j] += __shfl_xor(acc[j], 2, 64);
    acc[j] += __shfl_xor(acc[j], 4, 64);
    acc[j] += __shfl_xor(acc[j], 8, 64);
    acc[j] += __shfl_xor(acc[j], 16, 64);
    acc[j] += __shfl_xor(acc[j], 32, 64);
  }
  if (lane < 2) {
#pragma unroll
    for (int j = 0; j < 8; ++j) sRed[(rg * 8 + j) * 4 + wave] = acc[j];
  }
  __syncthreads();
  if (tid < ROWS) {
    float C = sRed[tid * 4] + sRed[tid * 4 + 1] + sRed[tid * 4 + 2] +
              sRed[tid * 4 + 3];
    sCost[tid] = rowscale[(size_t)b * NPTS + t0 + tid] * C;
  }
  __syncthreads();
  if (tid == 0) {
    float t = 0.0f;
#pragma unroll
    for (int i = 0; i < ROWS; ++i) t += sCost[i];
    atomicAdd(out + b, t);
  }
}

// ---------------------------------------------------------------------------
extern "C" void kernel_launch(void* const* d_in, const int* in_sizes, int n_in,
                              void* d_out, int out_size, void* d_ws, size_t ws_size,
                              hipStream_t stream) {
  const float* xyz1 = (const float*)d_in[0];
  const float* xyz2 = (const float*)d_in[1];
  float* out = (float*)d_out;
  float* ws = (float*)d_ws;

  float* remainL  = ws;                                   // B*N
  float* remainR  = ws + BATCH * NPTS;                    // B*M
  float* rowscale = ws + BATCH * NPTS + BATCH * MPTS;     // B*N
  float* colcoef  = ws + 2 * BATCH * NPTS + BATCH * MPTS; // B*M

  // levels[l] = -4^(7-l) for l=0..8; level 9 (=0) handled in C9
  const float levels[9] = {-16384.f, -4096.f, -1024.f, -256.f, -64.f,
                           -16.f,    -4.f,    -1.f,    -0.25f};
  dim3 grid(BATCH * (NPTS / ROWS));  // 1024 blocks

  emd_A0_kernel<<<grid, BLOCK, 0, stream>>>(xyz1, xyz2, rowscale, out);

  for (int l = 0; l < 9; ++l) {
    float L2C = levels[l] * LOG2E;
    float L2A = 0.25f * L2C;  // next level = lvl/4 (exact powers of 4)
    if (l == 0) {
      emd_B_kernel<true><<<grid, BLOCK, 0, stream>>>(xyz1, xyz2, rowscale,
                                                     remainR, colcoef, L2C);
      emd_CA_kernel<true, false><<<grid, BLOCK, 0, stream>>>(
          xyz1, xyz2, rowscale, remainL, remainR, colcoef, out, L2C, L2A);
    } else if (l < 8) {
      emd_B_kernel<false><<<grid, BLOCK, 0, stream>>>(xyz1, xyz2, rowscale,
                                                      remainR, colcoef, L2C);
      emd_CA_kernel<false, false><<<grid, BLOCK, 0, stream>>>(
          xyz1, xyz2, rowscale, remainL, remainR, colcoef, out, L2C, L2A);
    } else {
      emd_B_kernel<false><<<grid, BLOCK, 0, stream>>>(xyz1, xyz2, rowscale,
                                                      remainR, colcoef, L2C);
      emd_CA_kernel<false, true><<<grid, BLOCK, 0, stream>>>(
          xyz1, xyz2, rowscale, remainL, remainR, colcoef, out, L2C, 0.0f);
    }
  }
  emd_C9_kernel<<<grid, BLOCK, 0, stream>>>(xyz1, xyz2, rowscale, remainR, out);
}

// Round 11
// 446.194 us; speedup vs baseline: 1.0733x; 1.0733x over previous
//
#include <hip/hip_runtime.h>
#include <hip/hip_fp16.h>

// EMD approx-match (auction) + match_cost. [B,N,M] match never materialized;
// O(B*N) state in d_ws. 20 kernels: A0, {B(l), CA(l)} l=0..8, C9.
//
// R11 = R6-proven structure (AoS float4 LDS staging, scalar rint-split exp2,
// 2-Newton sqrt, R6 unroll pragmas) + three audited deltas:
//  1. ldexpf -> __builtin_amdgcn_ldexpf (guaranteed 1x v_ldexp_f32; if ldexpf
//     was an __ocml libcall this is the hidden 2x in every inner loop)
//  2. scaled-coordinate staging: coords pre-multiplied by k=sqrt(-L2) so the
//     exp2 argument is -(dx^2+dy^2+dz^2) (neg = free VOP3 modifier); deletes
//     the per-pair L2*d2 multiply. CA's cost-sqrt unscaled by 1/k once in the
//     epilogue (linear, exact).
//  3. B9 kernel removed: CA8 epilogue atomicAdds each block's 16 new rowscale
//     values (block-reduced, 1 atomic/block) into t1buf[b]; C9 reads the
//     scalar and computes colcoef during staging (R10-proven).
// R10 post-mortem: fold-with-per-block-re-reduction + unroll4 regressed
// (479 vs 458); both reverted.

#define BATCH 8
#define NPTS 2048
#define MPTS 2048
#define BLOCK 256
#define ROWS 16
#define LOG2E 1.44269504088896340736f

// Pure-VALU 2^x, x <= 0 (|x| up to ~4e6). rndne split + deg-4 Taylor +
// single-instruction v_ldexp_f32 (handles huge negative exponent -> 0).
__device__ __forceinline__ float fast_exp2(float x) {
  float rn = __builtin_rintf(x);        // v_rndne_f32
  float g = x - rn;                     // g in [-0.5, 0.5]
  float p = __builtin_fmaf(
      g,
      __builtin_fmaf(
          g,
          __builtin_fmaf(g,
                         __builtin_fmaf(g, 0.009618129107628477f,
                                        0.05550410866482158f),
                         0.2402265069591007f),
          0.6931471805599453f),
      1.0f);
  return __builtin_amdgcn_ldexpf(p, (int)rn);  // v_cvt_i32 + v_ldexp_f32
}

// Pure-VALU sqrt(a), a >= 0. Bit-hack rsqrt seed + 2 Newton; a=0 -> 0. ~1e-5.
__device__ __forceinline__ float fast_sqrt(float a) {
  int i = 0x5f3759df - (__builtin_bit_cast(int, a) >> 1);
  float y = __builtin_bit_cast(float, i);
  float h = 0.5f * a;
  y = y * __builtin_fmaf(-h * y, y, 1.5f);
  y = y * __builtin_fmaf(-h * y, y, 1.5f);
  return a * y;
}

// ---------------------------------------------------------------------------
// A0: rowscale[b,n] = 1/(sum_m exp(lvl0*d2) + 1e-9). Zeroes out[] and t1buf[].
// Coords staged pre-scaled by k0 = sqrt(-lvl0*LOG2E): exp2 arg = -s.
__global__ __launch_bounds__(BLOCK, 4) void emd_A0_kernel(
    const float* __restrict__ xyz1, const float* __restrict__ xyz2,
    float* __restrict__ rowscale, float* __restrict__ out,
    float* __restrict__ t1buf, float k0) {
  __shared__ float4 sP[MPTS];
  __shared__ float sRed[ROWS * 4];

  const int tid = threadIdx.x;
  const int bid = blockIdx.x;
  const int b = bid >> 7;
  const int t0 = (bid & 127) * ROWS;
  if (bid == 0 && tid < BATCH) { out[tid] = 0.0f; t1buf[tid] = 0.0f; }

  for (int m = tid; m < MPTS; m += BLOCK) {
    const float* p = xyz2 + ((size_t)b * MPTS + m) * 3;
    sP[m] = make_float4(k0 * p[0], k0 * p[1], k0 * p[2], 0.0f);
  }
  __syncthreads();

  const int wave = tid >> 6, lane = tid & 63;
  const int phase = lane >> 1, rg = lane & 1;
  const int r0 = t0 + rg * 8;
  float x1[8], y1[8], z1[8], acc[8];
#pragma unroll
  for (int j = 0; j < 8; ++j) {
    const float* p = xyz1 + ((size_t)b * NPTS + r0 + j) * 3;
    x1[j] = k0 * p[0]; y1[j] = k0 * p[1]; z1[j] = k0 * p[2]; acc[j] = 0.0f;
  }
  const int mb = wave * 512 + phase;
#pragma unroll 2
  for (int it = 0; it < 16; ++it) {
    float4 v = sP[mb + it * 32];
#pragma unroll
    for (int j = 0; j < 8; ++j) {
      float dx = x1[j] - v.x, dy = y1[j] - v.y, dz = z1[j] - v.z;
      float s = __builtin_fmaf(dx, dx, __builtin_fmaf(dy, dy, dz * dz));
      acc[j] += fast_exp2(-s);
    }
  }
#pragma unroll
  for (int j = 0; j < 8; ++j) {
    acc[j] += __shfl_xor(acc[j], 2, 64);
    acc[j] += __shfl_xor(acc[j], 4, 64);
    acc[j] += __shfl_xor(acc[j], 8, 64);
    acc[j] += __shfl_xor(acc[j], 16, 64);
    acc[j] += __shfl_xor(acc[j], 32, 64);
  }
  if (lane < 2) {
#pragma unroll
    for (int j = 0; j < 8; ++j) sRed[(rg * 8 + j) * 4 + wave] = acc[j];
  }
  __syncthreads();
  if (tid < ROWS) {
    float s = sRed[tid * 4] + sRed[tid * 4 + 1] + sRed[tid * 4 + 2] +
              sRed[tid * 4 + 3];
    rowscale[(size_t)b * NPTS + t0 + tid] = 1.0f / (s + 1e-9f);
  }
}

// ---------------------------------------------------------------------------
// B(l): col pass. t1 = sum_n exp(lvl*d2)*rs[n]; colsum = rr*t1;
// cs = min(rr/(colsum+1e-9),1); colcoef = rr*cs; remainR = max(rr-colsum*cs,0)
// Coords staged pre-scaled by k = sqrt(-L2C).
template <bool FIRST>
__global__ __launch_bounds__(BLOCK, 4) void emd_B_kernel(
    const float* __restrict__ xyz1, const float* __restrict__ xyz2,
    const float* __restrict__ rowscale, float* __restrict__ remainR,
    float* __restrict__ colcoef, float k) {
  __shared__ float4 sP[NPTS];   // (k*x1, k*y1, k*z1, rowscale)
  __shared__ float sRed[ROWS * 4];

  const int tid = threadIdx.x;
  const int bid = blockIdx.x;
  const int b = bid >> 7;
  const int t0 = (bid & 127) * ROWS;

  for (int n = tid; n < NPTS; n += BLOCK) {
    const float* p = xyz1 + ((size_t)b * NPTS + n) * 3;
    sP[n] = make_float4(k * p[0], k * p[1], k * p[2], rowscale[b * NPTS + n]);
  }
  __syncthreads();

  const int wave = tid >> 6, lane = tid & 63;
  const int phase = lane >> 1, rg = lane & 1;
  const int c0 = t0 + rg * 8;
  float x2[8], y2[8], z2[8], acc[8];
#pragma unroll
  for (int j = 0; j < 8; ++j) {
    const float* p = xyz2 + ((size_t)b * MPTS + c0 + j) * 3;
    x2[j] = k * p[0]; y2[j] = k * p[1]; z2[j] = k * p[2]; acc[j] = 0.0f;
  }
  const int nb = wave * 512 + phase;
#pragma unroll 2
  for (int it = 0; it < 16; ++it) {
    float4 v = sP[nb + it * 32];
#pragma unroll
    for (int j = 0; j < 8; ++j) {
      float dx = x2[j] - v.x, dy = y2[j] - v.y, dz = z2[j] - v.z;
      float s = __builtin_fmaf(dx, dx, __builtin_fmaf(dy, dy, dz * dz));
      acc[j] = __builtin_fmaf(fast_exp2(-s), v.w, acc[j]);
    }
  }
#pragma unroll
  for (int j = 0; j < 8; ++j) {
    acc[j] += __shfl_xor(acc[j], 2, 64);
    acc[j] += __shfl_xor(acc[j], 4, 64);
    acc[j] += __shfl_xor(acc[j], 8, 64);
    acc[j] += __shfl_xor(acc[j], 16, 64);
    acc[j] += __shfl_xor(acc[j], 32, 64);
  }
  if (lane < 2) {
#pragma unroll
    for (int j = 0; j < 8; ++j) sRed[(rg * 8 + j) * 4 + wave] = acc[j];
  }
  __syncthreads();
  if (tid < ROWS) {
    float t1 = sRed[tid * 4] + sRed[tid * 4 + 1] + sRed[tid * 4 + 2] +
               sRed[tid * 4 + 3];
    size_t idx = (size_t)b * MPTS + t0 + tid;
    float rr = FIRST ? 1.0f : remainR[idx];
    float colsum = rr * t1;
    float cs = fminf(rr / (colsum + 1e-9f), 1.0f);
    colcoef[idx] = rr * cs;
    remainR[idx] = fmaxf(rr - colsum * cs, 0.0f);
  }
}

// ---------------------------------------------------------------------------
// CA(l): row pass: cost(l) + remainL update + rowscale(l+1).
// Coords pre-scaled by kS = sqrt(-L2A) (non-LAST) or sqrt(-L2C) (LAST).
// non-LAST: e2 = exp2(-s); e1 = e2^4 (since L2C = 4*L2A).
// LAST:     e1 = exp2(-s); e2 = 1 (next lvl = 0).
// Cost sqrt uses scaled s: true sqrt = fast_sqrt(s) * invK, folded into the
// epilogue as sCost = rs*C*invK. LAST also atomicAdds this block's summed new
// rowscale into t1buf[b] (one atomic per block) for C9.
template <bool FIRST, bool LAST>
__global__ __launch_bounds__(BLOCK, 4) void emd_CA_kernel(
    const float* __restrict__ xyz1, const float* __restrict__ xyz2,
    float* __restrict__ rowscale, float* __restrict__ remainL,
    const float* __restrict__ remainR, const float* __restrict__ colcoef,
    float* __restrict__ out, float* __restrict__ t1buf, float kS, float invK) {
  __shared__ float4 sP[MPTS];   // (kS*x2, kS*y2, kS*z2, half2(cc, rr))
  __shared__ float sRedS[ROWS * 4];
  __shared__ float sRedC[ROWS * 4];
  __shared__ float sRedR[ROWS * 4];
  __shared__ float sCost[ROWS];
  __shared__ float sRs[ROWS];

  const int tid = threadIdx.x;
  const int bid = blockIdx.x;
  const int b = bid >> 7;
  const int t0 = (bid & 127) * ROWS;

  for (int m = tid; m < MPTS; m += BLOCK) {
    size_t idx = (size_t)b * MPTS + m;
    const float* p = xyz2 + idx * 3;
    __half2 h = __halves2half2(__float2half_rn(colcoef[idx]),
                               __float2half_rn(remainR[idx]));
    sP[m] = make_float4(kS * p[0], kS * p[1], kS * p[2],
                        __builtin_bit_cast(float, h));
  }
  __syncthreads();

  const int wave = tid >> 6, lane = tid & 63;
  const int phase = lane >> 2, rg = lane & 3;
  const int r0 = t0 + rg * 4;
  float x1[4], y1[4], z1[4];
#pragma unroll
  for (int j = 0; j < 4; ++j) {
    const float* p = xyz1 + ((size_t)b * NPTS + r0 + j) * 3;
    x1[j] = kS * p[0]; y1[j] = kS * p[1]; z1[j] = kS * p[2];
  }
  float accS[4] = {0.f, 0.f, 0.f, 0.f};
  float accC[4] = {0.f, 0.f, 0.f, 0.f};
  float accR[4] = {0.f, 0.f, 0.f, 0.f};
  const int mb = wave * 512 + phase;
#pragma unroll 4
  for (int it = 0; it < 32; ++it) {
    float4 v = sP[mb + it * 16];
    __half2 h = __builtin_bit_cast(__half2, v.w);
    float cc = __low2float(h);
    float rr = __high2float(h);
#pragma unroll
    for (int j = 0; j < 4; ++j) {
      float dx = x1[j] - v.x, dy = y1[j] - v.y, dz = z1[j] - v.z;
      float s = __builtin_fmaf(dx, dx, __builtin_fmaf(dy, dy, dz * dz));
      float sq = fast_sqrt(s);          // = kS * sqrt(d2); unscaled in epilogue
      float e1, e2;
      if (LAST) {
        e2 = 1.0f;
        e1 = fast_exp2(-s);
      } else {
        e2 = fast_exp2(-s);
        float e2s = e2 * e2;
        e1 = e2s * e2s;                 // exp(4*lvlA*d2) == exp(lvlC*d2)
      }
      float t = e1 * cc;
      accS[j] += t;
      accC[j] = __builtin_fmaf(t, sq, accC[j]);
      if (LAST) accR[j] += rr;
      else      accR[j] = __builtin_fmaf(e2, rr, accR[j]);
    }
  }
#pragma unroll
  for (int j = 0; j < 4; ++j) {
    accS[j] += __shfl_xor(accS[j], 4, 64);
    accS[j] += __shfl_xor(accS[j], 8, 64);
    accS[j] += __shfl_xor(accS[j], 16, 64);
    accS[j] += __shfl_xor(accS[j], 32, 64);
    accC[j] += __shfl_xor(accC[j], 4, 64);
    accC[j] += __shfl_xor(accC[j], 8, 64);
    accC[j] += __shfl_xor(accC[j], 16, 64);
    accC[j] += __shfl_xor(accC[j], 32, 64);
    accR[j] += __shfl_xor(accR[j], 4, 64);
    accR[j] += __shfl_xor(accR[j], 8, 64);
    accR[j] += __shfl_xor(accR[j], 16, 64);
    accR[j] += __shfl_xor(accR[j], 32, 64);
  }
  if (lane < 4) {
#pragma unroll
    for (int j = 0; j < 4; ++j) {
      sRedS[(rg * 4 + j) * 4 + wave] = accS[j];
      sRedC[(rg * 4 + j) * 4 + wave] = accC[j];
      sRedR[(rg * 4 + j) * 4 + wave] = accR[j];
    }
  }
  __syncthreads();
  if (tid < ROWS) {
    float S2 = sRedS[tid * 4] + sRedS[tid * 4 + 1] + sRedS[tid * 4 + 2] +
               sRedS[tid * 4 + 3];
    float C = sRedC[tid * 4] + sRedC[tid * 4 + 1] + sRedC[tid * 4 + 2] +
              sRedC[tid * 4 + 3];
    float R = sRedR[tid * 4] + sRedR[tid * 4 + 1] + sRedR[tid * 4 + 2] +
              sRedR[tid * 4 + 3];
    size_t idx = (size_t)b * NPTS + t0 + tid;
    float rs = rowscale[idx];
    float rl = FIRST ? 1.0f : remainL[idx];
    float rlN = fmaxf(rl - rs * S2, 0.0f);
    remainL[idx] = rlN;
    float rsN = rlN / (R + 1e-9f);
    rowscale[idx] = rsN;                // next level's rowscale
    sCost[tid] = rs * C * invK;         // unscale the sqrt here (linear)
    if (LAST) sRs[tid] = rsN;
  }
  __syncthreads();
  if (tid == 0) {
    float t = 0.0f;
#pragma unroll
    for (int i = 0; i < ROWS; ++i) t += sCost[i];
    atomicAdd(out + b, t);
    if (LAST) {
      float r = 0.0f;
#pragma unroll
      for (int i = 0; i < ROWS; ++i) r += sRs[i];
      atomicAdd(t1buf + b, r);          // t1 = sum_n rowscale(level9)
    }
  }
}

// ---------------------------------------------------------------------------
// C9 (lvl=0): t1 read from t1buf[b] (accumulated by CA8); colcoef computed
// during staging; cost[b] += rs[n] * sum_m cc[m]*sqrt(d2). Unscaled coords.
__global__ __launch_bounds__(BLOCK, 4) void emd_C9_kernel(
    const float* __restrict__ xyz1, const float* __restrict__ xyz2,
    const float* __restrict__ rowscale, const float* __restrict__ remainR,
    const float* __restrict__ t1buf, float* __restrict__ out) {
  __shared__ float4 sP[MPTS];   // (x2,y2,z2, colcoef)
  __shared__ float sRed[ROWS * 4];
  __shared__ float sCost[ROWS];

  const int tid = threadIdx.x;
  const int bid = blockIdx.x;
  const int b = bid >> 7;
  const int t0 = (bid & 127) * ROWS;
  const int wave = tid >> 6, lane = tid & 63;
  const float t1 = t1buf[b];

  for (int m = tid; m < MPTS; m += BLOCK) {
    size_t idx = (size_t)b * MPTS + m;
    const float* p = xyz2 + idx * 3;
    float rr = remainR[idx];
    float colsum = rr * t1;
    float cs = fminf(rr / (colsum + 1e-9f), 1.0f);
    sP[m] = make_float4(p[0], p[1], p[2], rr * cs);
  }
  __syncthreads();

  const int phase = lane >> 1, rg = lane & 1;
  const int r0 = t0 + rg * 8;
  float x1[8], y1[8], z1[8], acc[8];
#pragma unroll
  for (int j = 0; j < 8; ++j) {
    const float* p = xyz1 + ((size_t)b * NPTS + r0 + j) * 3;
    x1[j] = p[0]; y1[j] = p[1]; z1[j] = p[2]; acc[j] = 0.0f;
  }
  const int mb = wave * 512 + phase;
#pragma unroll 2
  for (int it = 0; it < 16; ++it) {
    float4 v = sP[mb + it * 32];
#pragma unroll
    for (int j = 0; j < 8; ++j) {
      float dx = x1[j] - v.x, dy = y1[j] - v.y, dz = z1[j] - v.z;
      float d2 = __builtin_fmaf(dx, dx, __builtin_fmaf(dy, dy, dz * dz));
      acc[j] = __builtin_fmaf(fast_sqrt(d2), v.w, acc[j]);
    }
  }
#pragma unroll
  for (int j = 0; j < 8; ++j) {
    acc[j] += __shfl_xor(acc[j], 2, 64);
    acc[j] += __shfl_xor(acc[j], 4, 64);
    acc[j] += __shfl_xor(acc[j], 8, 64);
    acc[j] += __shfl_xor(acc[j], 16, 64);
    acc[j] += __shfl_xor(acc[j], 32, 64);
  }
  if (lane < 2) {
#pragma unroll
    for (int j = 0; j < 8; ++j) sRed[(rg * 8 + j) * 4 + wave] = acc[j];
  }
  __syncthreads();
  if (tid < ROWS) {
    float C = sRed[tid * 4] + sRed[tid * 4 + 1] + sRed[tid * 4 + 2] +
              sRed[tid * 4 + 3];
    sCost[tid] = rowscale[(size_t)b * NPTS + t0 + tid] * C;
  }
  __syncthreads();
  if (tid == 0) {
    float t = 0.0f;
#pragma unroll
    for (int i = 0; i < ROWS; ++i) t += sCost[i];
    atomicAdd(out + b, t);
  }
}

// ---------------------------------------------------------------------------
extern "C" void kernel_launch(void* const* d_in, const int* in_sizes, int n_in,
                              void* d_out, int out_size, void* d_ws, size_t ws_size,
                              hipStream_t stream) {
  const float* xyz1 = (const float*)d_in[0];
  const float* xyz2 = (const float*)d_in[1];
  float* out = (float*)d_out;
  float* ws = (float*)d_ws;

  float* remainL  = ws;                                   // B*N
  float* remainR  = ws + BATCH * NPTS;                    // B*M
  float* rowscale = ws + BATCH * NPTS + BATCH * MPTS;     // B*N
  float* colcoef  = ws + 2 * BATCH * NPTS + BATCH * MPTS; // B*M
  float* t1buf    = ws + 3 * BATCH * NPTS + BATCH * MPTS; // BATCH

  // levels[l] = -4^(7-l) for l=0..8; level 9 (=0) handled in C9
  const float levels[9] = {-16384.f, -4096.f, -1024.f, -256.f, -64.f,
                           -16.f,    -4.f,    -1.f,    -0.25f};
  dim3 grid(BATCH * (NPTS / ROWS));  // 1024 blocks

  emd_A0_kernel<<<grid, BLOCK, 0, stream>>>(
      xyz1, xyz2, rowscale, out, t1buf, sqrtf(-levels[0] * LOG2E));

  for (int l = 0; l < 9; ++l) {
    float kB = sqrtf(-levels[l] * LOG2E);            // B pass scale
    float kA = 0.5f * kB;                            // sqrt(0.25*(-L2C))
    if (l == 0) {
      emd_B_kernel<true><<<grid, BLOCK, 0, stream>>>(xyz1, xyz2, rowscale,
                                                     remainR, colcoef, kB);
      emd_CA_kernel<true, false><<<grid, BLOCK, 0, stream>>>(
          xyz1, xyz2, rowscale, remainL, remainR, colcoef, out, t1buf,
          kA, 1.0f / kA);
    } else if (l < 8) {
      emd_B_kernel<false><<<grid, BLOCK, 0, stream>>>(xyz1, xyz2, rowscale,
                                                      remainR, colcoef, kB);
      emd_CA_kernel<false, false><<<grid, BLOCK, 0, stream>>>(
          xyz1, xyz2, rowscale, remainL, remainR, colcoef, out, t1buf,
          kA, 1.0f / kA);
    } else {
      emd_B_kernel<false><<<grid, BLOCK, 0, stream>>>(xyz1, xyz2, rowscale,
                                                      remainR, colcoef, kB);
      // LAST: scale by kB (e1 = exp2(-s) directly), next level = 0
      emd_CA_kernel<false, true><<<grid, BLOCK, 0, stream>>>(
          xyz1, xyz2, rowscale, remainL, remainR, colcoef, out, t1buf,
          kB, 1.0f / kB);
    }
  }
  emd_C9_kernel<<<grid, BLOCK, 0, stream>>>(xyz1, xyz2, rowscale, remainR,
                                            t1buf, out);
}

// Round 12
// 438.198 us; speedup vs baseline: 1.0929x; 1.0182x over previous
//
#include <hip/hip_runtime.h>
#include <hip/hip_fp16.h>

// EMD approx-match (auction) + match_cost. [B,N,M] match never materialized;
// O(B*N) state in d_ws. 20 kernels: A0, {B(l), CA(l)} l=0..8, C9.
//
// R12 = R11 (scaled-coord staging, __builtin_amdgcn_ldexpf exp2, t1buf fold)
// with ALL global reads vectorized to float4 (xyz is [N][3] contiguous: 4
// points = 3 aligned float4s; weights are aligned float4 runs). Staging
// drops 32->8 VMEM insts/thread, register coord loads 24->6 (A0/B/C9) and
// 12->3 (CA). Arithmetic values and FP order are IDENTICAL to R11 (absmax
// must stay 4.0). LDS layout untouched (AoS float4 sP — NOT the failed
// R7-R9 v2f-LDS-cast pattern; these are aligned GLOBAL float4 loads).

#define BATCH 8
#define NPTS 2048
#define MPTS 2048
#define BLOCK 256
#define ROWS 16
#define LOG2E 1.44269504088896340736f

// Pure-VALU 2^x, x <= 0. rndne split + deg-4 Taylor + v_ldexp_f32. ~4e-5 rel.
__device__ __forceinline__ float fast_exp2(float x) {
  float rn = __builtin_rintf(x);
  float g = x - rn;                     // g in [-0.5, 0.5]
  float p = __builtin_fmaf(
      g,
      __builtin_fmaf(
          g,
          __builtin_fmaf(g,
                         __builtin_fmaf(g, 0.009618129107628477f,
                                        0.05550410866482158f),
                         0.2402265069591007f),
          0.6931471805599453f),
      1.0f);
  return __builtin_amdgcn_ldexpf(p, (int)rn);
}

// Pure-VALU sqrt(a), a >= 0. Bit-hack rsqrt seed + 2 Newton; a=0 -> 0. ~1e-5.
__device__ __forceinline__ float fast_sqrt(float a) {
  int i = 0x5f3759df - (__builtin_bit_cast(int, a) >> 1);
  float y = __builtin_bit_cast(float, i);
  float h = 0.5f * a;
  y = y * __builtin_fmaf(-h * y, y, 1.5f);
  y = y * __builtin_fmaf(-h * y, y, 1.5f);
  return a * y;
}

__device__ __forceinline__ float packh2(float c, float r) {
  __half2 h = __halves2half2(__float2half_rn(c), __float2half_rn(r));
  return __builtin_bit_cast(float, h);
}

// Load 8 consecutive points (r0 multiple of 8) as 6 float4s, scaled by k.
__device__ __forceinline__ void load8(const float4* q, int r0, float k,
                                      float* x, float* y, float* z) {
  int b4 = (r0 >> 2) * 3;
  float4 q0 = q[b4], q1 = q[b4 + 1], q2 = q[b4 + 2];
  float4 q3 = q[b4 + 3], q4 = q[b4 + 4], q5 = q[b4 + 5];
  x[0] = k * q0.x; y[0] = k * q0.y; z[0] = k * q0.z;
  x[1] = k * q0.w; y[1] = k * q1.x; z[1] = k * q1.y;
  x[2] = k * q1.z; y[2] = k * q1.w; z[2] = k * q2.x;
  x[3] = k * q2.y; y[3] = k * q2.z; z[3] = k * q2.w;
  x[4] = k * q3.x; y[4] = k * q3.y; z[4] = k * q3.z;
  x[5] = k * q3.w; y[5] = k * q4.x; z[5] = k * q4.y;
  x[6] = k * q4.z; y[6] = k * q4.w; z[6] = k * q5.x;
  x[7] = k * q5.y; y[7] = k * q5.z; z[7] = k * q5.w;
}

// ---------------------------------------------------------------------------
// A0: rowscale[b,n] = 1/(sum_m exp(lvl0*d2) + 1e-9). Zeroes out[]/t1buf[].
__global__ __launch_bounds__(BLOCK, 4) void emd_A0_kernel(
    const float* __restrict__ xyz1, const float* __restrict__ xyz2,
    float* __restrict__ rowscale, float* __restrict__ out,
    float* __restrict__ t1buf, float k0) {
  __shared__ float4 sP[MPTS];
  __shared__ float sRed[ROWS * 4];

  const int tid = threadIdx.x;
  const int bid = blockIdx.x;
  const int b = bid >> 7;
  const int t0 = (bid & 127) * ROWS;
  if (bid == 0 && tid < BATCH) { out[tid] = 0.0f; t1buf[tid] = 0.0f; }

  const float4* q2 = (const float4*)(xyz2 + (size_t)b * MPTS * 3);
  for (int g = tid; g < MPTS / 4; g += BLOCK) {
    float4 a = q2[3 * g], bb = q2[3 * g + 1], c = q2[3 * g + 2];
    sP[4 * g + 0] = make_float4(k0 * a.x, k0 * a.y, k0 * a.z, 0.0f);
    sP[4 * g + 1] = make_float4(k0 * a.w, k0 * bb.x, k0 * bb.y, 0.0f);
    sP[4 * g + 2] = make_float4(k0 * bb.z, k0 * bb.w, k0 * c.x, 0.0f);
    sP[4 * g + 3] = make_float4(k0 * c.y, k0 * c.z, k0 * c.w, 0.0f);
  }
  __syncthreads();

  const int wave = tid >> 6, lane = tid & 63;
  const int phase = lane >> 1, rg = lane & 1;
  const int r0 = t0 + rg * 8;
  float x1[8], y1[8], z1[8], acc[8];
  load8((const float4*)(xyz1 + (size_t)b * NPTS * 3), r0, k0, x1, y1, z1);
#pragma unroll
  for (int j = 0; j < 8; ++j) acc[j] = 0.0f;
  const int mb = wave * 512 + phase;
#pragma unroll 2
  for (int it = 0; it < 16; ++it) {
    float4 v = sP[mb + it * 32];
#pragma unroll
    for (int j = 0; j < 8; ++j) {
      float dx = x1[j] - v.x, dy = y1[j] - v.y, dz = z1[j] - v.z;
      float s = __builtin_fmaf(dx, dx, __builtin_fmaf(dy, dy, dz * dz));
      acc[j] += fast_exp2(-s);
    }
  }
#pragma unroll
  for (int j = 0; j < 8; ++j) {
    acc[j] += __shfl_xor(acc[j], 2, 64);
    acc[j] += __shfl_xor(acc[j], 4, 64);
    acc[j] += __shfl_xor(acc[j], 8, 64);
    acc[j] += __shfl_xor(acc[j], 16, 64);
    acc[j] += __shfl_xor(acc[j], 32, 64);
  }
  if (lane < 2) {
#pragma unroll
    for (int j = 0; j < 8; ++j) sRed[(rg * 8 + j) * 4 + wave] = acc[j];
  }
  __syncthreads();
  if (tid < ROWS) {
    float s = sRed[tid * 4] + sRed[tid * 4 + 1] + sRed[tid * 4 + 2] +
              sRed[tid * 4 + 3];
    rowscale[(size_t)b * NPTS + t0 + tid] = 1.0f / (s + 1e-9f);
  }
}

// ---------------------------------------------------------------------------
// B(l): col pass. t1 = sum_n exp(lvl*d2)*rs[n]; colsum = rr*t1;
// cs = min(rr/(colsum+1e-9),1); colcoef = rr*cs; remainR = max(rr-colsum*cs,0)
template <bool FIRST>
__global__ __launch_bounds__(BLOCK, 4) void emd_B_kernel(
    const float* __restrict__ xyz1, const float* __restrict__ xyz2,
    const float* __restrict__ rowscale, float* __restrict__ remainR,
    float* __restrict__ colcoef, float k) {
  __shared__ float4 sP[NPTS];   // (k*x1, k*y1, k*z1, rowscale)
  __shared__ float sRed[ROWS * 4];

  const int tid = threadIdx.x;
  const int bid = blockIdx.x;
  const int b = bid >> 7;
  const int t0 = (bid & 127) * ROWS;

  const float4* q1 = (const float4*)(xyz1 + (size_t)b * NPTS * 3);
  const float4* w4 = (const float4*)(rowscale + (size_t)b * NPTS);
  for (int g = tid; g < NPTS / 4; g += BLOCK) {
    float4 a = q1[3 * g], bb = q1[3 * g + 1], c = q1[3 * g + 2];
    float4 w = w4[g];
    sP[4 * g + 0] = make_float4(k * a.x, k * a.y, k * a.z, w.x);
    sP[4 * g + 1] = make_float4(k * a.w, k * bb.x, k * bb.y, w.y);
    sP[4 * g + 2] = make_float4(k * bb.z, k * bb.w, k * c.x, w.z);
    sP[4 * g + 3] = make_float4(k * c.y, k * c.z, k * c.w, w.w);
  }
  __syncthreads();

  const int wave = tid >> 6, lane = tid & 63;
  const int phase = lane >> 1, rg = lane & 1;
  const int c0 = t0 + rg * 8;
  float x2[8], y2[8], z2[8], acc[8];
  load8((const float4*)(xyz2 + (size_t)b * MPTS * 3), c0, k, x2, y2, z2);
#pragma unroll
  for (int j = 0; j < 8; ++j) acc[j] = 0.0f;
  const int nb = wave * 512 + phase;
#pragma unroll 2
  for (int it = 0; it < 16; ++it) {
    float4 v = sP[nb + it * 32];
#pragma unroll
    for (int j = 0; j < 8; ++j) {
      float dx = x2[j] - v.x, dy = y2[j] - v.y, dz = z2[j] - v.z;
      float s = __builtin_fmaf(dx, dx, __builtin_fmaf(dy, dy, dz * dz));
      acc[j] = __builtin_fmaf(fast_exp2(-s), v.w, acc[j]);
    }
  }
#pragma unroll
  for (int j = 0; j < 8; ++j) {
    acc[j] += __shfl_xor(acc[j], 2, 64);
    acc[j] += __shfl_xor(acc[j], 4, 64);
    acc[j] += __shfl_xor(acc[j], 8, 64);
    acc[j] += __shfl_xor(acc[j], 16, 64);
    acc[j] += __shfl_xor(acc[j], 32, 64);
  }
  if (lane < 2) {
#pragma unroll
    for (int j = 0; j < 8; ++j) sRed[(rg * 8 + j) * 4 + wave] = acc[j];
  }
  __syncthreads();
  if (tid < ROWS) {
    float t1 = sRed[tid * 4] + sRed[tid * 4 + 1] + sRed[tid * 4 + 2] +
               sRed[tid * 4 + 3];
    size_t idx = (size_t)b * MPTS + t0 + tid;
    float rr = FIRST ? 1.0f : remainR[idx];
    float colsum = rr * t1;
    float cs = fminf(rr / (colsum + 1e-9f), 1.0f);
    colcoef[idx] = rr * cs;
    remainR[idx] = fmaxf(rr - colsum * cs, 0.0f);
  }
}

// ---------------------------------------------------------------------------
// CA(l): row pass: cost(l) + remainL update + rowscale(l+1).
// non-LAST: e2 = exp2(-s); e1 = e2^4. LAST: e1 = exp2(-s); e2 = 1.
// Cost sqrt unscaled by invK in epilogue. LAST atomicAdds summed new
// rowscale into t1buf[b] for C9.
template <bool FIRST, bool LAST>
__global__ __launch_bounds__(BLOCK, 4) void emd_CA_kernel(
    const float* __restrict__ xyz1, const float* __restrict__ xyz2,
    float* __restrict__ rowscale, float* __restrict__ remainL,
    const float* __restrict__ remainR, const float* __restrict__ colcoef,
    float* __restrict__ out, float* __restrict__ t1buf, float kS, float invK) {
  __shared__ float4 sP[MPTS];   // (kS*x2, kS*y2, kS*z2, half2(cc, rr))
  __shared__ float sRedS[ROWS * 4];
  __shared__ float sRedC[ROWS * 4];
  __shared__ float sRedR[ROWS * 4];
  __shared__ float sCost[ROWS];
  __shared__ float sRs[ROWS];

  const int tid = threadIdx.x;
  const int bid = blockIdx.x;
  const int b = bid >> 7;
  const int t0 = (bid & 127) * ROWS;

  const float4* q2 = (const float4*)(xyz2 + (size_t)b * MPTS * 3);
  const float4* cc4 = (const float4*)(colcoef + (size_t)b * MPTS);
  const float4* rr4 = (const float4*)(remainR + (size_t)b * MPTS);
  for (int g = tid; g < MPTS / 4; g += BLOCK) {
    float4 a = q2[3 * g], bb = q2[3 * g + 1], c = q2[3 * g + 2];
    float4 cc = cc4[g], rr = rr4[g];
    sP[4 * g + 0] = make_float4(kS * a.x, kS * a.y, kS * a.z, packh2(cc.x, rr.x));
    sP[4 * g + 1] = make_float4(kS * a.w, kS * bb.x, kS * bb.y, packh2(cc.y, rr.y));
    sP[4 * g + 2] = make_float4(kS * bb.z, kS * bb.w, kS * c.x, packh2(cc.z, rr.z));
    sP[4 * g + 3] = make_float4(kS * c.y, kS * c.z, kS * c.w, packh2(cc.w, rr.w));
  }
  __syncthreads();

  const int wave = tid >> 6, lane = tid & 63;
  const int phase = lane >> 2, rg = lane & 3;
  const int r0 = t0 + rg * 4;
  float x1[4], y1[4], z1[4];
  {
    const float4* q1 = (const float4*)(xyz1 + (size_t)b * NPTS * 3);
    int b4 = (r0 >> 2) * 3;
    float4 a = q1[b4], bb = q1[b4 + 1], c = q1[b4 + 2];
    x1[0] = kS * a.x;  y1[0] = kS * a.y;  z1[0] = kS * a.z;
    x1[1] = kS * a.w;  y1[1] = kS * bb.x; z1[1] = kS * bb.y;
    x1[2] = kS * bb.z; y1[2] = kS * bb.w; z1[2] = kS * c.x;
    x1[3] = kS * c.y;  y1[3] = kS * c.z;  z1[3] = kS * c.w;
  }
  float accS[4] = {0.f, 0.f, 0.f, 0.f};
  float accC[4] = {0.f, 0.f, 0.f, 0.f};
  float accR[4] = {0.f, 0.f, 0.f, 0.f};
  const int mb = wave * 512 + phase;
#pragma unroll 4
  for (int it = 0; it < 32; ++it) {
    float4 v = sP[mb + it * 16];
    __half2 h = __builtin_bit_cast(__half2, v.w);
    float cc = __low2float(h);
    float rr = __high2float(h);
#pragma unroll
    for (int j = 0; j < 4; ++j) {
      float dx = x1[j] - v.x, dy = y1[j] - v.y, dz = z1[j] - v.z;
      float s = __builtin_fmaf(dx, dx, __builtin_fmaf(dy, dy, dz * dz));
      float sq = fast_sqrt(s);
      float e1, e2;
      if (LAST) {
        e2 = 1.0f;
        e1 = fast_exp2(-s);
      } else {
        e2 = fast_exp2(-s);
        float e2s = e2 * e2;
        e1 = e2s * e2s;
      }
      float t = e1 * cc;
      accS[j] += t;
      accC[j] = __builtin_fmaf(t, sq, accC[j]);
      if (LAST) accR[j] += rr;
      else      accR[j] = __builtin_fmaf(e2, rr, accR[j]);
    }
  }
#pragma unroll
  for (int j = 0; j < 4; ++j) {
    accS[j] += __shfl_xor(accS[j], 4, 64);
    accS[j] += __shfl_xor(accS[j], 8, 64);
    accS[j] += __shfl_xor(accS[j], 16, 64);
    accS[j] += __shfl_xor(accS[j], 32, 64);
    accC[j] += __shfl_xor(accC[j], 4, 64);
    accC[j] += __shfl_xor(accC[j], 8, 64);
    accC[j] += __shfl_xor(accC[j], 16, 64);
    accC[j] += __shfl_xor(accC[j], 32, 64);
    accR[j] += __shfl_xor(accR[j], 4, 64);
    accR[j] += __shfl_xor(accR[j], 8, 64);
    accR[j] += __shfl_xor(accR[j], 16, 64);
    accR[j] += __shfl_xor(accR[j], 32, 64);
  }
  if (lane < 4) {
#pragma unroll
    for (int j = 0; j < 4; ++j) {
      sRedS[(rg * 4 + j) * 4 + wave] = accS[j];
      sRedC[(rg * 4 + j) * 4 + wave] = accC[j];
      sRedR[(rg * 4 + j) * 4 + wave] = accR[j];
    }
  }
  __syncthreads();
  if (tid < ROWS) {
    float S2 = sRedS[tid * 4] + sRedS[tid * 4 + 1] + sRedS[tid * 4 + 2] +
               sRedS[tid * 4 + 3];
    float C = sRedC[tid * 4] + sRedC[tid * 4 + 1] + sRedC[tid * 4 + 2] +
              sRedC[tid * 4 + 3];
    float R = sRedR[tid * 4] + sRedR[tid * 4 + 1] + sRedR[tid * 4 + 2] +
              sRedR[tid * 4 + 3];
    size_t idx = (size_t)b * NPTS + t0 + tid;
    float rs = rowscale[idx];
    float rl = FIRST ? 1.0f : remainL[idx];
    float rlN = fmaxf(rl - rs * S2, 0.0f);
    remainL[idx] = rlN;
    float rsN = rlN / (R + 1e-9f);
    rowscale[idx] = rsN;
    sCost[tid] = rs * C * invK;
    if (LAST) sRs[tid] = rsN;
  }
  __syncthreads();
  if (tid == 0) {
    float t = 0.0f;
#pragma unroll
    for (int i = 0; i < ROWS; ++i) t += sCost[i];
    atomicAdd(out + b, t);
    if (LAST) {
      float r = 0.0f;
#pragma unroll
      for (int i = 0; i < ROWS; ++i) r += sRs[i];
      atomicAdd(t1buf + b, r);
    }
  }
}

// ---------------------------------------------------------------------------
// C9 (lvl=0): t1 from t1buf[b]; colcoef computed during staging;
// cost[b] += rs[n] * sum_m cc[m]*sqrt(d2). Unscaled coords.
__global__ __launch_bounds__(BLOCK, 4) void emd_C9_kernel(
    const float* __restrict__ xyz1, const float* __restrict__ xyz2,
    const float* __restrict__ rowscale, const float* __restrict__ remainR,
    const float* __restrict__ t1buf, float* __restrict__ out) {
  __shared__ float4 sP[MPTS];   // (x2,y2,z2, colcoef)
  __shared__ float sRed[ROWS * 4];
  __shared__ float sCost[ROWS];

  const int tid = threadIdx.x;
  const int bid = blockIdx.x;
  const int b = bid >> 7;
  const int t0 = (bid & 127) * ROWS;
  const int wave = tid >> 6, lane = tid & 63;
  const float t1 = t1buf[b];

  const float4* q2 = (const float4*)(xyz2 + (size_t)b * MPTS * 3);
  const float4* rr4 = (const float4*)(remainR + (size_t)b * MPTS);
  for (int g = tid; g < MPTS / 4; g += BLOCK) {
    float4 a = q2[3 * g], bb = q2[3 * g + 1], c = q2[3 * g + 2];
    float4 rr = rr4[g];
    float w0 = rr.x * fminf(rr.x / (rr.x * t1 + 1e-9f), 1.0f);
    float w1 = rr.y * fminf(rr.y / (rr.y * t1 + 1e-9f), 1.0f);
    float w2 = rr.z * fminf(rr.z / (rr.z * t1 + 1e-9f), 1.0f);
    float w3 = rr.w * fminf(rr.w / (rr.w * t1 + 1e-9f), 1.0f);
    sP[4 * g + 0] = make_float4(a.x, a.y, a.z, w0);
    sP[4 * g + 1] = make_float4(a.w, bb.x, bb.y, w1);
    sP[4 * g + 2] = make_float4(bb.z, bb.w, c.x, w2);
    sP[4 * g + 3] = make_float4(c.y, c.z, c.w, w3);
  }
  __syncthreads();

  const int phase = lane >> 1, rg = lane & 1;
  const int r0 = t0 + rg * 8;
  float x1[8], y1[8], z1[8], acc[8];
  load8((const float4*)(xyz1 + (size_t)b * NPTS * 3), r0, 1.0f, x1, y1, z1);
#pragma unroll
  for (int j = 0; j < 8; ++j) acc[j] = 0.0f;
  const int mb = wave * 512 + phase;
#pragma unroll 2
  for (int it = 0; it < 16; ++it) {
    float4 v = sP[mb + it * 32];
#pragma unroll
    for (int j = 0; j < 8; ++j) {
      float dx = x1[j] - v.x, dy = y1[j] - v.y, dz = z1[j] - v.z;
      float d2 = __builtin_fmaf(dx, dx, __builtin_fmaf(dy, dy, dz * dz));
      acc[j] = __builtin_fmaf(fast_sqrt(d2), v.w, acc[j]);
    }
  }
#pragma unroll
  for (int j = 0; j < 8; ++j) {
    acc[j] += __shfl_xor(acc[j], 2, 64);
    acc[j] += __shfl_xor(acc[j], 4, 64);
    acc[j] += __shfl_xor(acc[j], 8, 64);
    acc[j] += __shfl_xor(acc[j], 16, 64);
    acc[j] += __shfl_xor(acc[j], 32, 64);
  }
  if (lane < 2) {
#pragma unroll
    for (int j = 0; j < 8; ++j) sRed[(rg * 8 + j) * 4 + wave] = acc[j];
  }
  __syncthreads();
  if (tid < ROWS) {
    float C = sRed[tid * 4] + sRed[tid * 4 + 1] + sRed[tid * 4 + 2] +
              sRed[tid * 4 + 3];
    sCost[tid] = rowscale[(size_t)b * NPTS + t0 + tid] * C;
  }
  __syncthreads();
  if (tid == 0) {
    float t = 0.0f;
#pragma unroll
    for (int i = 0; i < ROWS; ++i) t += sCost[i];
    atomicAdd(out + b, t);
  }
}

// ---------------------------------------------------------------------------
extern "C" void kernel_launch(void* const* d_in, const int* in_sizes, int n_in,
                              void* d_out, int out_size, void* d_ws, size_t ws_size,
                              hipStream_t stream) {
  const float* xyz1 = (const float*)d_in[0];
  const float* xyz2 = (const float*)d_in[1];
  float* out = (float*)d_out;
  float* ws = (float*)d_ws;

  float* remainL  = ws;                                   // B*N
  float* remainR  = ws + BATCH * NPTS;                    // B*M
  float* rowscale = ws + BATCH * NPTS + BATCH * MPTS;     // B*N
  float* colcoef  = ws + 2 * BATCH * NPTS + BATCH * MPTS; // B*M
  float* t1buf    = ws + 3 * BATCH * NPTS + BATCH * MPTS; // BATCH

  const float levels[9] = {-16384.f, -4096.f, -1024.f, -256.f, -64.f,
                           -16.f,    -4.f,    -1.f,    -0.25f};
  dim3 grid(BATCH * (NPTS / ROWS));  // 1024 blocks

  emd_A0_kernel<<<grid, BLOCK, 0, stream>>>(
      xyz1, xyz2, rowscale, out, t1buf, sqrtf(-levels[0] * LOG2E));

  for (int l = 0; l < 9; ++l) {
    float kB = sqrtf(-levels[l] * LOG2E);
    float kA = 0.5f * kB;
    if (l == 0) {
      emd_B_kernel<true><<<grid, BLOCK, 0, stream>>>(xyz1, xyz2, rowscale,
                                                     remainR, colcoef, kB);
      emd_CA_kernel<true, false><<<grid, BLOCK, 0, stream>>>(
          xyz1, xyz2, rowscale, remainL, remainR, colcoef, out, t1buf,
          kA, 1.0f / kA);
    } else if (l < 8) {
      emd_B_kernel<false><<<grid, BLOCK, 0, stream>>>(xyz1, xyz2, rowscale,
                                                      remainR, colcoef, kB);
      emd_CA_kernel<false, false><<<grid, BLOCK, 0, stream>>>(
          xyz1, xyz2, rowscale, remainL, remainR, colcoef, out, t1buf,
          kA, 1.0f / kA);
    } else {
      emd_B_kernel<false><<<grid, BLOCK, 0, stream>>>(xyz1, xyz2, rowscale,
                                                      remainR, colcoef, kB);
      emd_CA_kernel<false, true><<<grid, BLOCK, 0, stream>>>(
          xyz1, xyz2, rowscale, remainL, remainR, colcoef, out, t1buf,
          kB, 1.0f / kB);
    }
  }
  emd_C9_kernel<<<grid, BLOCK, 0, stream>>>(xyz1, xyz2, rowscale, remainR,
                                            t1buf, out);
}

// Round 13
// 368.200 us; speedup vs baseline: 1.3007x; 1.1901x over previous
//
#include <hip/hip_runtime.h>
#include <hip/hip_fp16.h>

// EMD approx-match (auction) + match_cost. [B,N,M] match never materialized;
// O(B*N) state in d_ws. 20 kernels: A0, {B(l), CA(l)} l=0..8, C9.
//
// R13 = R12 (scaled-coord staging, float4 global loads, t1buf fold, e2^4
// dedup) with hardware transcendentals: exp2 -> single v_exp_f32, sqrt ->
// single v_sqrt_f32. R6's "trans serialize" claim was a model fit made under
// the (now falsified) F~=0 per-kernel-overhead assumption; re-fit attributes
// R3->R6's win to the e2^4 dedup, not VALU-izing exp. Trans unit at quarter
// rate = ~8 cyc/wave64 issue vs 16 (VALU exp2) / 14 (VALU sqrt): per-pair
// issue drops B 15->9, CA 25->13 ops. Accuracy improves (v_exp ~1 ulp).

#define BATCH 8
#define NPTS 2048
#define MPTS 2048
#define BLOCK 256
#define ROWS 16
#define LOG2E 1.44269504088896340736f

__device__ __forceinline__ float fast_exp2(float x) {
  return __builtin_amdgcn_exp2f(x);     // v_exp_f32 (2^x), ~1 ulp
}

__device__ __forceinline__ float fast_sqrt(float a) {
  return __builtin_amdgcn_sqrtf(a);     // v_sqrt_f32
}

__device__ __forceinline__ float packh2(float c, float r) {
  __half2 h = __halves2half2(__float2half_rn(c), __float2half_rn(r));
  return __builtin_bit_cast(float, h);
}

// Load 8 consecutive points (r0 multiple of 8) as 6 float4s, scaled by k.
__device__ __forceinline__ void load8(const float4* q, int r0, float k,
                                      float* x, float* y, float* z) {
  int b4 = (r0 >> 2) * 3;
  float4 q0 = q[b4], q1 = q[b4 + 1], q2 = q[b4 + 2];
  float4 q3 = q[b4 + 3], q4 = q[b4 + 4], q5 = q[b4 + 5];
  x[0] = k * q0.x; y[0] = k * q0.y; z[0] = k * q0.z;
  x[1] = k * q0.w; y[1] = k * q1.x; z[1] = k * q1.y;
  x[2] = k * q1.z; y[2] = k * q1.w; z[2] = k * q2.x;
  x[3] = k * q2.y; y[3] = k * q2.z; z[3] = k * q2.w;
  x[4] = k * q3.x; y[4] = k * q3.y; z[4] = k * q3.z;
  x[5] = k * q3.w; y[5] = k * q4.x; z[5] = k * q4.y;
  x[6] = k * q4.z; y[6] = k * q4.w; z[6] = k * q5.x;
  x[7] = k * q5.y; y[7] = k * q5.z; z[7] = k * q5.w;
}

// ---------------------------------------------------------------------------
// A0: rowscale[b,n] = 1/(sum_m exp(lvl0*d2) + 1e-9). Zeroes out[]/t1buf[].
__global__ __launch_bounds__(BLOCK, 4) void emd_A0_kernel(
    const float* __restrict__ xyz1, const float* __restrict__ xyz2,
    float* __restrict__ rowscale, float* __restrict__ out,
    float* __restrict__ t1buf, float k0) {
  __shared__ float4 sP[MPTS];
  __shared__ float sRed[ROWS * 4];

  const int tid = threadIdx.x;
  const int bid = blockIdx.x;
  const int b = bid >> 7;
  const int t0 = (bid & 127) * ROWS;
  if (bid == 0 && tid < BATCH) { out[tid] = 0.0f; t1buf[tid] = 0.0f; }

  const float4* q2 = (const float4*)(xyz2 + (size_t)b * MPTS * 3);
  for (int g = tid; g < MPTS / 4; g += BLOCK) {
    float4 a = q2[3 * g], bb = q2[3 * g + 1], c = q2[3 * g + 2];
    sP[4 * g + 0] = make_float4(k0 * a.x, k0 * a.y, k0 * a.z, 0.0f);
    sP[4 * g + 1] = make_float4(k0 * a.w, k0 * bb.x, k0 * bb.y, 0.0f);
    sP[4 * g + 2] = make_float4(k0 * bb.z, k0 * bb.w, k0 * c.x, 0.0f);
    sP[4 * g + 3] = make_float4(k0 * c.y, k0 * c.z, k0 * c.w, 0.0f);
  }
  __syncthreads();

  const int wave = tid >> 6, lane = tid & 63;
  const int phase = lane >> 1, rg = lane & 1;
  const int r0 = t0 + rg * 8;
  float x1[8], y1[8], z1[8], acc[8];
  load8((const float4*)(xyz1 + (size_t)b * NPTS * 3), r0, k0, x1, y1, z1);
#pragma unroll
  for (int j = 0; j < 8; ++j) acc[j] = 0.0f;
  const int mb = wave * 512 + phase;
#pragma unroll 2
  for (int it = 0; it < 16; ++it) {
    float4 v = sP[mb + it * 32];
#pragma unroll
    for (int j = 0; j < 8; ++j) {
      float dx = x1[j] - v.x, dy = y1[j] - v.y, dz = z1[j] - v.z;
      float s = __builtin_fmaf(dx, dx, __builtin_fmaf(dy, dy, dz * dz));
      acc[j] += fast_exp2(-s);
    }
  }
#pragma unroll
  for (int j = 0; j < 8; ++j) {
    acc[j] += __shfl_xor(acc[j], 2, 64);
    acc[j] += __shfl_xor(acc[j], 4, 64);
    acc[j] += __shfl_xor(acc[j], 8, 64);
    acc[j] += __shfl_xor(acc[j], 16, 64);
    acc[j] += __shfl_xor(acc[j], 32, 64);
  }
  if (lane < 2) {
#pragma unroll
    for (int j = 0; j < 8; ++j) sRed[(rg * 8 + j) * 4 + wave] = acc[j];
  }
  __syncthreads();
  if (tid < ROWS) {
    float s = sRed[tid * 4] + sRed[tid * 4 + 1] + sRed[tid * 4 + 2] +
              sRed[tid * 4 + 3];
    rowscale[(size_t)b * NPTS + t0 + tid] = 1.0f / (s + 1e-9f);
  }
}

// ---------------------------------------------------------------------------
// B(l): col pass. t1 = sum_n exp(lvl*d2)*rs[n]; colsum = rr*t1;
// cs = min(rr/(colsum+1e-9),1); colcoef = rr*cs; remainR = max(rr-colsum*cs,0)
template <bool FIRST>
__global__ __launch_bounds__(BLOCK, 4) void emd_B_kernel(
    const float* __restrict__ xyz1, const float* __restrict__ xyz2,
    const float* __restrict__ rowscale, float* __restrict__ remainR,
    float* __restrict__ colcoef, float k) {
  __shared__ float4 sP[NPTS];   // (k*x1, k*y1, k*z1, rowscale)
  __shared__ float sRed[ROWS * 4];

  const int tid = threadIdx.x;
  const int bid = blockIdx.x;
  const int b = bid >> 7;
  const int t0 = (bid & 127) * ROWS;

  const float4* q1 = (const float4*)(xyz1 + (size_t)b * NPTS * 3);
  const float4* w4 = (const float4*)(rowscale + (size_t)b * NPTS);
  for (int g = tid; g < NPTS / 4; g += BLOCK) {
    float4 a = q1[3 * g], bb = q1[3 * g + 1], c = q1[3 * g + 2];
    float4 w = w4[g];
    sP[4 * g + 0] = make_float4(k * a.x, k * a.y, k * a.z, w.x);
    sP[4 * g + 1] = make_float4(k * a.w, k * bb.x, k * bb.y, w.y);
    sP[4 * g + 2] = make_float4(k * bb.z, k * bb.w, k * c.x, w.z);
    sP[4 * g + 3] = make_float4(k * c.y, k * c.z, k * c.w, w.w);
  }
  __syncthreads();

  const int wave = tid >> 6, lane = tid & 63;
  const int phase = lane >> 1, rg = lane & 1;
  const int c0 = t0 + rg * 8;
  float x2[8], y2[8], z2[8], acc[8];
  load8((const float4*)(xyz2 + (size_t)b * MPTS * 3), c0, k, x2, y2, z2);
#pragma unroll
  for (int j = 0; j < 8; ++j) acc[j] = 0.0f;
  const int nb = wave * 512 + phase;
#pragma unroll 2
  for (int it = 0; it < 16; ++it) {
    float4 v = sP[nb + it * 32];
#pragma unroll
    for (int j = 0; j < 8; ++j) {
      float dx = x2[j] - v.x, dy = y2[j] - v.y, dz = z2[j] - v.z;
      float s = __builtin_fmaf(dx, dx, __builtin_fmaf(dy, dy, dz * dz));
      acc[j] = __builtin_fmaf(fast_exp2(-s), v.w, acc[j]);
    }
  }
#pragma unroll
  for (int j = 0; j < 8; ++j) {
    acc[j] += __shfl_xor(acc[j], 2, 64);
    acc[j] += __shfl_xor(acc[j], 4, 64);
    acc[j] += __shfl_xor(acc[j], 8, 64);
    acc[j] += __shfl_xor(acc[j], 16, 64);
    acc[j] += __shfl_xor(acc[j], 32, 64);
  }
  if (lane < 2) {
#pragma unroll
    for (int j = 0; j < 8; ++j) sRed[(rg * 8 + j) * 4 + wave] = acc[j];
  }
  __syncthreads();
  if (tid < ROWS) {
    float t1 = sRed[tid * 4] + sRed[tid * 4 + 1] + sRed[tid * 4 + 2] +
               sRed[tid * 4 + 3];
    size_t idx = (size_t)b * MPTS + t0 + tid;
    float rr = FIRST ? 1.0f : remainR[idx];
    float colsum = rr * t1;
    float cs = fminf(rr / (colsum + 1e-9f), 1.0f);
    colcoef[idx] = rr * cs;
    remainR[idx] = fmaxf(rr - colsum * cs, 0.0f);
  }
}

// ---------------------------------------------------------------------------
// CA(l): row pass: cost(l) + remainL update + rowscale(l+1).
// non-LAST: e2 = exp2(-s); e1 = e2^4. LAST: e1 = exp2(-s); e2 = 1.
// Cost sqrt unscaled by invK in epilogue. LAST atomicAdds summed new
// rowscale into t1buf[b] for C9.
template <bool FIRST, bool LAST>
__global__ __launch_bounds__(BLOCK, 4) void emd_CA_kernel(
    const float* __restrict__ xyz1, const float* __restrict__ xyz2,
    float* __restrict__ rowscale, float* __restrict__ remainL,
    const float* __restrict__ remainR, const float* __restrict__ colcoef,
    float* __restrict__ out, float* __restrict__ t1buf, float kS, float invK) {
  __shared__ float4 sP[MPTS];   // (kS*x2, kS*y2, kS*z2, half2(cc, rr))
  __shared__ float sRedS[ROWS * 4];
  __shared__ float sRedC[ROWS * 4];
  __shared__ float sRedR[ROWS * 4];
  __shared__ float sCost[ROWS];
  __shared__ float sRs[ROWS];

  const int tid = threadIdx.x;
  const int bid = blockIdx.x;
  const int b = bid >> 7;
  const int t0 = (bid & 127) * ROWS;

  const float4* q2 = (const float4*)(xyz2 + (size_t)b * MPTS * 3);
  const float4* cc4 = (const float4*)(colcoef + (size_t)b * MPTS);
  const float4* rr4 = (const float4*)(remainR + (size_t)b * MPTS);
  for (int g = tid; g < MPTS / 4; g += BLOCK) {
    float4 a = q2[3 * g], bb = q2[3 * g + 1], c = q2[3 * g + 2];
    float4 cc = cc4[g], rr = rr4[g];
    sP[4 * g + 0] = make_float4(kS * a.x, kS * a.y, kS * a.z, packh2(cc.x, rr.x));
    sP[4 * g + 1] = make_float4(kS * a.w, kS * bb.x, kS * bb.y, packh2(cc.y, rr.y));
    sP[4 * g + 2] = make_float4(kS * bb.z, kS * bb.w, kS * c.x, packh2(cc.z, rr.z));
    sP[4 * g + 3] = make_float4(kS * c.y, kS * c.z, kS * c.w, packh2(cc.w, rr.w));
  }
  __syncthreads();

  const int wave = tid >> 6, lane = tid & 63;
  const int phase = lane >> 2, rg = lane & 3;
  const int r0 = t0 + rg * 4;
  float x1[4], y1[4], z1[4];
  {
    const float4* q1 = (const float4*)(xyz1 + (size_t)b * NPTS * 3);
    int b4 = (r0 >> 2) * 3;
    float4 a = q1[b4], bb = q1[b4 + 1], c = q1[b4 + 2];
    x1[0] = kS * a.x;  y1[0] = kS * a.y;  z1[0] = kS * a.z;
    x1[1] = kS * a.w;  y1[1] = kS * bb.x; z1[1] = kS * bb.y;
    x1[2] = kS * bb.z; y1[2] = kS * bb.w; z1[2] = kS * c.x;
    x1[3] = kS * c.y;  y1[3] = kS * c.z;  z1[3] = kS * c.w;
  }
  float accS[4] = {0.f, 0.f, 0.f, 0.f};
  float accC[4] = {0.f, 0.f, 0.f, 0.f};
  float accR[4] = {0.f, 0.f, 0.f, 0.f};
  const int mb = wave * 512 + phase;
#pragma unroll 4
  for (int it = 0; it < 32; ++it) {
    float4 v = sP[mb + it * 16];
    __half2 h = __builtin_bit_cast(__half2, v.w);
    float cc = __low2float(h);
    float rr = __high2float(h);
#pragma unroll
    for (int j = 0; j < 4; ++j) {
      float dx = x1[j] - v.x, dy = y1[j] - v.y, dz = z1[j] - v.z;
      float s = __builtin_fmaf(dx, dx, __builtin_fmaf(dy, dy, dz * dz));
      float sq = fast_sqrt(s);
      float e1, e2;
      if (LAST) {
        e2 = 1.0f;
        e1 = fast_exp2(-s);
      } else {
        e2 = fast_exp2(-s);
        float e2s = e2 * e2;
        e1 = e2s * e2s;
      }
      float t = e1 * cc;
      accS[j] += t;
      accC[j] = __builtin_fmaf(t, sq, accC[j]);
      if (LAST) accR[j] += rr;
      else      accR[j] = __builtin_fmaf(e2, rr, accR[j]);
    }
  }
#pragma unroll
  for (int j = 0; j < 4; ++j) {
    accS[j] += __shfl_xor(accS[j], 4, 64);
    accS[j] += __shfl_xor(accS[j], 8, 64);
    accS[j] += __shfl_xor(accS[j], 16, 64);
    accS[j] += __shfl_xor(accS[j], 32, 64);
    accC[j] += __shfl_xor(accC[j], 4, 64);
    accC[j] += __shfl_xor(accC[j], 8, 64);
    accC[j] += __shfl_xor(accC[j], 16, 64);
    accC[j] += __shfl_xor(accC[j], 32, 64);
    accR[j] += __shfl_xor(accR[j], 4, 64);
    accR[j] += __shfl_xor(accR[j], 8, 64);
    accR[j] += __shfl_xor(accR[j], 16, 64);
    accR[j] += __shfl_xor(accR[j], 32, 64);
  }
  if (lane < 4) {
#pragma unroll
    for (int j = 0; j < 4; ++j) {
      sRedS[(rg * 4 + j) * 4 + wave] = accS[j];
      sRedC[(rg * 4 + j) * 4 + wave] = accC[j];
      sRedR[(rg * 4 + j) * 4 + wave] = accR[j];
    }
  }
  __syncthreads();
  if (tid < ROWS) {
    float S2 = sRedS[tid * 4] + sRedS[tid * 4 + 1] + sRedS[tid * 4 + 2] +
               sRedS[tid * 4 + 3];
    float C = sRedC[tid * 4] + sRedC[tid * 4 + 1] + sRedC[tid * 4 + 2] +
              sRedC[tid * 4 + 3];
    float R = sRedR[tid * 4] + sRedR[tid * 4 + 1] + sRedR[tid * 4 + 2] +
              sRedR[tid * 4 + 3];
    size_t idx = (size_t)b * NPTS + t0 + tid;
    float rs = rowscale[idx];
    float rl = FIRST ? 1.0f : remainL[idx];
    float rlN = fmaxf(rl - rs * S2, 0.0f);
    remainL[idx] = rlN;
    float rsN = rlN / (R + 1e-9f);
    rowscale[idx] = rsN;
    sCost[tid] = rs * C * invK;
    if (LAST) sRs[tid] = rsN;
  }
  __syncthreads();
  if (tid == 0) {
    float t = 0.0f;
#pragma unroll
    for (int i = 0; i < ROWS; ++i) t += sCost[i];
    atomicAdd(out + b, t);
    if (LAST) {
      float r = 0.0f;
#pragma unroll
      for (int i = 0; i < ROWS; ++i) r += sRs[i];
      atomicAdd(t1buf + b, r);
    }
  }
}

// ---------------------------------------------------------------------------
// C9 (lvl=0): t1 from t1buf[b]; colcoef computed during staging;
// cost[b] += rs[n] * sum_m cc[m]*sqrt(d2). Unscaled coords.
__global__ __launch_bounds__(BLOCK, 4) void emd_C9_kernel(
    const float* __restrict__ xyz1, const float* __restrict__ xyz2,
    const float* __restrict__ rowscale, const float* __restrict__ remainR,
    const float* __restrict__ t1buf, float* __restrict__ out) {
  __shared__ float4 sP[MPTS];   // (x2,y2,z2, colcoef)
  __shared__ float sRed[ROWS * 4];
  __shared__ float sCost[ROWS];

  const int tid = threadIdx.x;
  const int bid = blockIdx.x;
  const int b = bid >> 7;
  const int t0 = (bid & 127) * ROWS;
  const int wave = tid >> 6, lane = tid & 63;
  const float t1 = t1buf[b];

  const float4* q2 = (const float4*)(xyz2 + (size_t)b * MPTS * 3);
  const float4* rr4 = (const float4*)(remainR + (size_t)b * MPTS);
  for (int g = tid; g < MPTS / 4; g += BLOCK) {
    float4 a = q2[3 * g], bb = q2[3 * g + 1], c = q2[3 * g + 2];
    float4 rr = rr4[g];
    float w0 = rr.x * fminf(rr.x / (rr.x * t1 + 1e-9f), 1.0f);
    float w1 = rr.y * fminf(rr.y / (rr.y * t1 + 1e-9f), 1.0f);
    float w2 = rr.z * fminf(rr.z / (rr.z * t1 + 1e-9f), 1.0f);
    float w3 = rr.w * fminf(rr.w / (rr.w * t1 + 1e-9f), 1.0f);
    sP[4 * g + 0] = make_float4(a.x, a.y, a.z, w0);
    sP[4 * g + 1] = make_float4(a.w, bb.x, bb.y, w1);
    sP[4 * g + 2] = make_float4(bb.z, bb.w, c.x, w2);
    sP[4 * g + 3] = make_float4(c.y, c.z, c.w, w3);
  }
  __syncthreads();

  const int phase = lane >> 1, rg = lane & 1;
  const int r0 = t0 + rg * 8;
  float x1[8], y1[8], z1[8], acc[8];
  load8((const float4*)(xyz1 + (size_t)b * NPTS * 3), r0, 1.0f, x1, y1, z1);
#pragma unroll
  for (int j = 0; j < 8; ++j) acc[j] = 0.0f;
  const int mb = wave * 512 + phase;
#pragma unroll 2
  for (int it = 0; it < 16; ++it) {
    float4 v = sP[mb + it * 32];
#pragma unroll
    for (int j = 0; j < 8; ++j) {
      float dx = x1[j] - v.x, dy = y1[j] - v.y, dz = z1[j] - v.z;
      float d2 = __builtin_fmaf(dx, dx, __builtin_fmaf(dy, dy, dz * dz));
      acc[j] = __builtin_fmaf(fast_sqrt(d2), v.w, acc[j]);
    }
  }
#pragma unroll
  for (int j = 0; j < 8; ++j) {
    acc[j] += __shfl_xor(acc[j], 2, 64);
    acc[j] += __shfl_xor(acc[j], 4, 64);
    acc[j] += __shfl_xor(acc[j], 8, 64);
    acc[j] += __shfl_xor(acc[j], 16, 64);
    acc[j] += __shfl_xor(acc[j], 32, 64);
  }
  if (lane < 2) {
#pragma unroll
    for (int j = 0; j < 8; ++j) sRed[(rg * 8 + j) * 4 + wave] = acc[j];
  }
  __syncthreads();
  if (tid < ROWS) {
    float C = sRed[tid * 4] + sRed[tid * 4 + 1] + sRed[tid * 4 + 2] +
              sRed[tid * 4 + 3];
    sCost[tid] = rowscale[(size_t)b * NPTS + t0 + tid] * C;
  }
  __syncthreads();
  if (tid == 0) {
    float t = 0.0f;
#pragma unroll
    for (int i = 0; i < ROWS; ++i) t += sCost[i];
    atomicAdd(out + b, t);
  }
}

// ---------------------------------------------------------------------------
extern "C" void kernel_launch(void* const* d_in, const int* in_sizes, int n_in,
                              void* d_out, int out_size, void* d_ws, size_t ws_size,
                              hipStream_t stream) {
  const float* xyz1 = (const float*)d_in[0];
  const float* xyz2 = (const float*)d_in[1];
  float* out = (float*)d_out;
  float* ws = (float*)d_ws;

  float* remainL  = ws;                                   // B*N
  float* remainR  = ws + BATCH * NPTS;                    // B*M
  float* rowscale = ws + BATCH * NPTS + BATCH * MPTS;     // B*N
  float* colcoef  = ws + 2 * BATCH * NPTS + BATCH * MPTS; // B*M
  float* t1buf    = ws + 3 * BATCH * NPTS + BATCH * MPTS; // BATCH

  const float levels[9] = {-16384.f, -4096.f, -1024.f, -256.f, -64.f,
                           -16.f,    -4.f,    -1.f,    -0.25f};
  dim3 grid(BATCH * (NPTS / ROWS));  // 1024 blocks

  emd_A0_kernel<<<grid, BLOCK, 0, stream>>>(
      xyz1, xyz2, rowscale, out, t1buf, sqrtf(-levels[0] * LOG2E));

  for (int l = 0; l < 9; ++l) {
    float kB = sqrtf(-levels[l] * LOG2E);
    float kA = 0.5f * kB;
    if (l == 0) {
      emd_B_kernel<true><<<grid, BLOCK, 0, stream>>>(xyz1, xyz2, rowscale,
                                                     remainR, colcoef, kB);
      emd_CA_kernel<true, false><<<grid, BLOCK, 0, stream>>>(
          xyz1, xyz2, rowscale, remainL, remainR, colcoef, out, t1buf,
          kA, 1.0f / kA);
    } else if (l < 8) {
      emd_B_kernel<false><<<grid, BLOCK, 0, stream>>>(xyz1, xyz2, rowscale,
                                                      remainR, colcoef, kB);
      emd_CA_kernel<false, false><<<grid, BLOCK, 0, stream>>>(
          xyz1, xyz2, rowscale, remainL, remainR, colcoef, out, t1buf,
          kA, 1.0f / kA);
    } else {
      emd_B_kernel<false><<<grid, BLOCK, 0, stream>>>(xyz1, xyz2, rowscale,
                                                      remainR, colcoef, kB);
      emd_CA_kernel<false, true><<<grid, BLOCK, 0, stream>>>(
          xyz1, xyz2, rowscale, remainL, remainR, colcoef, out, t1buf,
          kB, 1.0f / kB);
    }
  }
  emd_C9_kernel<<<grid, BLOCK, 0, stream>>>(xyz1, xyz2, rowscale, remainR,
                                            t1buf, out);
}

// Round 14
// 357.370 us; speedup vs baseline: 1.3401x; 1.0303x over previous
//
#include <hip/hip_runtime.h>
#include <hip/hip_fp16.h>

// EMD approx-match (auction) + match_cost. [B,N,M] match never materialized.
// R14: B-pass folded into CA via cross-kernel t1 accumulation -> 12 dispatches
// (memset, A0', CA'0..CA'8, C9) instead of 20. R13 budget fit: ~13us fixed
// per kernel boundary (multi-XCD L2 acquire/release) x 20 = ~255us dominated.
// t1_{l+1}[m] = sum_n e2(n,m)*rsN[n] is accumulated by CA'(l)'s second
// m-sweep (e2 already computed there) via device-scope atomicAdd; CA'(l+1)
// does the former B clipping elementwise during staging. remainR ping-pongs
// (race-free); t1 triple-buffers with rotating zeroing (buf[(l+2)%3] is idle
// at level l). Level-9 t1 degenerates to scalar sum (t9).

#define BATCH 8
#define NPTS 2048
#define MPTS 2048
#define BLOCK 256
#define ROWS 16
#define LOG2E 1.44269504088896340736f

__device__ __forceinline__ float fast_exp2(float x) {
  return __builtin_amdgcn_exp2f(x);     // v_exp_f32
}
__device__ __forceinline__ float fast_sqrt(float a) {
  return __builtin_amdgcn_sqrtf(a);     // v_sqrt_f32
}
__device__ __forceinline__ float packh2(float c, float r) {
  __half2 h = __halves2half2(__float2half_rn(c), __float2half_rn(r));
  return __builtin_bit_cast(float, h);
}

// Load 8 consecutive points (r0 multiple of 8) as 6 float4s, scaled by k.
__device__ __forceinline__ void load8(const float4* q, int r0, float k,
                                      float* x, float* y, float* z) {
  int b4 = (r0 >> 2) * 3;
  float4 q0 = q[b4], q1 = q[b4 + 1], q2 = q[b4 + 2];
  float4 q3 = q[b4 + 3], q4 = q[b4 + 4], q5 = q[b4 + 5];
  x[0] = k * q0.x; y[0] = k * q0.y; z[0] = k * q0.z;
  x[1] = k * q0.w; y[1] = k * q1.x; z[1] = k * q1.y;
  x[2] = k * q1.z; y[2] = k * q1.w; z[2] = k * q2.x;
  x[3] = k * q2.y; y[3] = k * q2.z; z[3] = k * q2.w;
  x[4] = k * q3.x; y[4] = k * q3.y; z[4] = k * q3.z;
  x[5] = k * q3.w; y[5] = k * q4.x; z[5] = k * q4.y;
  x[6] = k * q4.z; y[6] = k * q4.w; z[6] = k * q5.x;
  x[7] = k * q5.y; y[7] = k * q5.z; z[7] = k * q5.w;
}

// ---------------------------------------------------------------------------
// A0': rowscale_0[n] = 1/(sum_m exp(lvl0*d2) + 1e-9); then sweep2 accumulates
// t1_0[m] = sum_n e_0(n,m)*rs_0[n] into t1acc (pre-zeroed by memset).
// Designated blocks zero t1zero (=buf1, CA'0's accumulation target).
__global__ __launch_bounds__(BLOCK, 4) void emd_A0_kernel(
    const float* __restrict__ xyz1, const float* __restrict__ xyz2,
    float* __restrict__ rowscale, float* __restrict__ out,
    float* __restrict__ t9, float* __restrict__ t1acc,
    float* __restrict__ t1zero, float k0) {
  __shared__ float4 sP[MPTS];
  __shared__ float sRed[ROWS * 4];
  __shared__ float sRs[ROWS];

  const int tid = threadIdx.x;
  const int bid = blockIdx.x;
  const int b = bid >> 7;
  const int t0 = (bid & 127) * ROWS;
  const bool desig = (bid & 127) == 0;
  if (bid == 0 && tid < BATCH) { out[tid] = 0.0f; t9[tid] = 0.0f; }

  const float4* q2 = (const float4*)(xyz2 + (size_t)b * MPTS * 3);
  float4* z4 = (float4*)(t1zero + (size_t)b * MPTS);
  for (int g = tid; g < MPTS / 4; g += BLOCK) {
    float4 a = q2[3 * g], bb = q2[3 * g + 1], c = q2[3 * g + 2];
    sP[4 * g + 0] = make_float4(k0 * a.x, k0 * a.y, k0 * a.z, 0.0f);
    sP[4 * g + 1] = make_float4(k0 * a.w, k0 * bb.x, k0 * bb.y, 0.0f);
    sP[4 * g + 2] = make_float4(k0 * bb.z, k0 * bb.w, k0 * c.x, 0.0f);
    sP[4 * g + 3] = make_float4(k0 * c.y, k0 * c.z, k0 * c.w, 0.0f);
    if (desig) z4[g] = make_float4(0.f, 0.f, 0.f, 0.f);
  }
  __syncthreads();

  const int wave = tid >> 6, lane = tid & 63;
  const int phase = lane >> 1, rg = lane & 1;
  const int r0 = t0 + rg * 8;
  float x1[8], y1[8], z1[8], acc[8];
  load8((const float4*)(xyz1 + (size_t)b * NPTS * 3), r0, k0, x1, y1, z1);
#pragma unroll
  for (int j = 0; j < 8; ++j) acc[j] = 0.0f;
  const int mb = wave * 512 + phase;
#pragma unroll 2
  for (int it = 0; it < 16; ++it) {
    float4 v = sP[mb + it * 32];
#pragma unroll
    for (int j = 0; j < 8; ++j) {
      float dx = x1[j] - v.x, dy = y1[j] - v.y, dz = z1[j] - v.z;
      float s = __builtin_fmaf(dx, dx, __builtin_fmaf(dy, dy, dz * dz));
      acc[j] += fast_exp2(-s);
    }
  }
#pragma unroll
  for (int j = 0; j < 8; ++j) {
    acc[j] += __shfl_xor(acc[j], 2, 64);
    acc[j] += __shfl_xor(acc[j], 4, 64);
    acc[j] += __shfl_xor(acc[j], 8, 64);
    acc[j] += __shfl_xor(acc[j], 16, 64);
    acc[j] += __shfl_xor(acc[j], 32, 64);
  }
  if (lane < 2) {
#pragma unroll
    for (int j = 0; j < 8; ++j) sRed[(rg * 8 + j) * 4 + wave] = acc[j];
  }
  __syncthreads();
  if (tid < ROWS) {
    float s = sRed[tid * 4] + sRed[tid * 4 + 1] + sRed[tid * 4 + 2] +
              sRed[tid * 4 + 3];
    float rs = 1.0f / (s + 1e-9f);
    rowscale[(size_t)b * NPTS + t0 + tid] = rs;
    sRs[tid] = rs;
  }
  __syncthreads();

  // sweep2: t1_0 partials (this block's 16 rows) -> atomicAdd
  float rsn[8];
#pragma unroll
  for (int j = 0; j < 8; ++j) rsn[j] = sRs[rg * 8 + j];
  float* accb = t1acc + (size_t)b * MPTS;
#pragma unroll 2
  for (int it = 0; it < 16; ++it) {
    int idx = mb + it * 32;
    float4 v = sP[idx];
    float part = 0.0f;
#pragma unroll
    for (int j = 0; j < 8; ++j) {
      float dx = x1[j] - v.x, dy = y1[j] - v.y, dz = z1[j] - v.z;
      float s = __builtin_fmaf(dx, dx, __builtin_fmaf(dy, dy, dz * dz));
      part = __builtin_fmaf(fast_exp2(-s), rsn[j], part);
    }
    part += __shfl_xor(part, 1, 64);
    if (rg == 0) atomicAdd(accb + idx, part);
  }
}

// ---------------------------------------------------------------------------
// CA'(l): staging does the former B(l) clipping elementwise (rr_l + t1_l ->
// cc_l, rr_{l+1}; designated block writes rr_{l+1} and zeros t1Zero), then
// sweep1 = cost(l) + remainL + rowscale(l+1) (e1 = e2^4), then sweep2
// accumulates t1_{l+1}[m] = sum e2*rsN into t1Acc. LAST: e1 = exp2(-s)
// directly, t9 += sum rsN, no sweep2.
template <bool FIRST, bool LAST>
__global__ __launch_bounds__(BLOCK, 4) void emd_CA_kernel(
    const float* __restrict__ xyz1, const float* __restrict__ xyz2,
    float* __restrict__ rowscale, float* __restrict__ remainL,
    const float* __restrict__ rrIn, float* __restrict__ rrOut,
    const float* __restrict__ t1In, float* __restrict__ t1Acc,
    float* __restrict__ t1Zero, float* __restrict__ out,
    float* __restrict__ t9, float kS, float invK) {
  __shared__ float4 sP[MPTS];   // (kS*x2, kS*y2, kS*z2, half2(cc, rrN))
  __shared__ float sRedS[ROWS * 4];
  __shared__ float sRedC[ROWS * 4];
  __shared__ float sRedR[ROWS * 4];
  __shared__ float sCost[ROWS];
  __shared__ float sRs[ROWS];

  const int tid = threadIdx.x;
  const int bid = blockIdx.x;
  const int b = bid >> 7;
  const int t0 = (bid & 127) * ROWS;
  const bool desig = (bid & 127) == 0;

  const float4* q2 = (const float4*)(xyz2 + (size_t)b * MPTS * 3);
  const float4* rr4 = (const float4*)(rrIn + (size_t)b * MPTS);
  const float4* t14 = (const float4*)(t1In + (size_t)b * MPTS);
  float4* ro4 = (float4*)(rrOut + (size_t)b * MPTS);
  float4* z4 = LAST ? nullptr : (float4*)(t1Zero + (size_t)b * MPTS);
  for (int g = tid; g < MPTS / 4; g += BLOCK) {
    float4 a = q2[3 * g], bb = q2[3 * g + 1], c = q2[3 * g + 2];
    float4 t1v = t14[g];
    float4 rrv = FIRST ? make_float4(1.f, 1.f, 1.f, 1.f) : rr4[g];
    float cc[4], rn[4];
    float rrc[4] = {rrv.x, rrv.y, rrv.z, rrv.w};
    float t1c[4] = {t1v.x, t1v.y, t1v.z, t1v.w};
#pragma unroll
    for (int i = 0; i < 4; ++i) {
      float colsum = rrc[i] * t1c[i];
      float cs = fminf(rrc[i] / (colsum + 1e-9f), 1.0f);
      cc[i] = rrc[i] * cs;
      rn[i] = fmaxf(rrc[i] - colsum * cs, 0.0f);
    }
    sP[4 * g + 0] = make_float4(kS * a.x, kS * a.y, kS * a.z, packh2(cc[0], rn[0]));
    sP[4 * g + 1] = make_float4(kS * a.w, kS * bb.x, kS * bb.y, packh2(cc[1], rn[1]));
    sP[4 * g + 2] = make_float4(kS * bb.z, kS * bb.w, kS * c.x, packh2(cc[2], rn[2]));
    sP[4 * g + 3] = make_float4(kS * c.y, kS * c.z, kS * c.w, packh2(cc[3], rn[3]));
    if (desig) {
      ro4[g] = make_float4(rn[0], rn[1], rn[2], rn[3]);
      if (!LAST) z4[g] = make_float4(0.f, 0.f, 0.f, 0.f);
    }
  }
  __syncthreads();

  const int wave = tid >> 6, lane = tid & 63;
  const int phase = lane >> 2, rg = lane & 3;
  const int r0 = t0 + rg * 4;
  float x1[4], y1[4], z1[4];
  {
    const float4* q1 = (const float4*)(xyz1 + (size_t)b * NPTS * 3);
    int b4 = (r0 >> 2) * 3;
    float4 a = q1[b4], bb = q1[b4 + 1], c = q1[b4 + 2];
    x1[0] = kS * a.x;  y1[0] = kS * a.y;  z1[0] = kS * a.z;
    x1[1] = kS * a.w;  y1[1] = kS * bb.x; z1[1] = kS * bb.y;
    x1[2] = kS * bb.z; y1[2] = kS * bb.w; z1[2] = kS * c.x;
    x1[3] = kS * c.y;  y1[3] = kS * c.z;  z1[3] = kS * c.w;
  }
  float accS[4] = {0.f, 0.f, 0.f, 0.f};
  float accC[4] = {0.f, 0.f, 0.f, 0.f};
  float accR[4] = {0.f, 0.f, 0.f, 0.f};
  const int mb = wave * 512 + phase;
#pragma unroll 4
  for (int it = 0; it < 32; ++it) {
    float4 v = sP[mb + it * 16];
    __half2 h = __builtin_bit_cast(__half2, v.w);
    float cc = __low2float(h);
    float rr = __high2float(h);
#pragma unroll
    for (int j = 0; j < 4; ++j) {
      float dx = x1[j] - v.x, dy = y1[j] - v.y, dz = z1[j] - v.z;
      float s = __builtin_fmaf(dx, dx, __builtin_fmaf(dy, dy, dz * dz));
      float sq = fast_sqrt(s);
      float e1, e2;
      if (LAST) {
        e2 = 1.0f;
        e1 = fast_exp2(-s);
      } else {
        e2 = fast_exp2(-s);
        float e2s = e2 * e2;
        e1 = e2s * e2s;
      }
      float t = e1 * cc;
      accS[j] += t;
      accC[j] = __builtin_fmaf(t, sq, accC[j]);
      if (LAST) accR[j] += rr;
      else      accR[j] = __builtin_fmaf(e2, rr, accR[j]);
    }
  }
#pragma unroll
  for (int j = 0; j < 4; ++j) {
    accS[j] += __shfl_xor(accS[j], 4, 64);
    accS[j] += __shfl_xor(accS[j], 8, 64);
    accS[j] += __shfl_xor(accS[j], 16, 64);
    accS[j] += __shfl_xor(accS[j], 32, 64);
    accC[j] += __shfl_xor(accC[j], 4, 64);
    accC[j] += __shfl_xor(accC[j], 8, 64);
    accC[j] += __shfl_xor(accC[j], 16, 64);
    accC[j] += __shfl_xor(accC[j], 32, 64);
    accR[j] += __shfl_xor(accR[j], 4, 64);
    accR[j] += __shfl_xor(accR[j], 8, 64);
    accR[j] += __shfl_xor(accR[j], 16, 64);
    accR[j] += __shfl_xor(accR[j], 32, 64);
  }
  if (lane < 4) {
#pragma unroll
    for (int j = 0; j < 4; ++j) {
      sRedS[(rg * 4 + j) * 4 + wave] = accS[j];
      sRedC[(rg * 4 + j) * 4 + wave] = accC[j];
      sRedR[(rg * 4 + j) * 4 + wave] = accR[j];
    }
  }
  __syncthreads();
  if (tid < ROWS) {
    float S2 = sRedS[tid * 4] + sRedS[tid * 4 + 1] + sRedS[tid * 4 + 2] +
               sRedS[tid * 4 + 3];
    float C = sRedC[tid * 4] + sRedC[tid * 4 + 1] + sRedC[tid * 4 + 2] +
              sRedC[tid * 4 + 3];
    float R = sRedR[tid * 4] + sRedR[tid * 4 + 1] + sRedR[tid * 4 + 2] +
              sRedR[tid * 4 + 3];
    size_t idx = (size_t)b * NPTS + t0 + tid;
    float rs = rowscale[idx];
    float rl = FIRST ? 1.0f : remainL[idx];
    float rlN = fmaxf(rl - rs * S2, 0.0f);
    remainL[idx] = rlN;
    float rsN = rlN / (R + 1e-9f);
    rowscale[idx] = rsN;
    sCost[tid] = rs * C * invK;
    sRs[tid] = rsN;
  }
  __syncthreads();
  if (tid == 0) {
    float t = 0.0f;
#pragma unroll
    for (int i = 0; i < ROWS; ++i) t += sCost[i];
    atomicAdd(out + b, t);
    if (LAST) {
      float r = 0.0f;
#pragma unroll
      for (int i = 0; i < ROWS; ++i) r += sRs[i];
      atomicAdd(t9 + b, r);
    }
  }
  if (!LAST) {
    // sweep2: t1_{l+1} partials over this block's 16 rows
    float rsn[4];
#pragma unroll
    for (int j = 0; j < 4; ++j) rsn[j] = sRs[rg * 4 + j];
    float* accb = t1Acc + (size_t)b * MPTS;
#pragma unroll 4
    for (int it = 0; it < 32; ++it) {
      int idx = mb + it * 16;
      float4 v = sP[idx];
      float part = 0.0f;
#pragma unroll
      for (int j = 0; j < 4; ++j) {
        float dx = x1[j] - v.x, dy = y1[j] - v.y, dz = z1[j] - v.z;
        float s = __builtin_fmaf(dx, dx, __builtin_fmaf(dy, dy, dz * dz));
        part = __builtin_fmaf(fast_exp2(-s), rsn[j], part);
      }
      part += __shfl_xor(part, 1, 64);
      part += __shfl_xor(part, 2, 64);
      if (rg == 0) atomicAdd(accb + idx, part);
    }
  }
}

// ---------------------------------------------------------------------------
// C9 (lvl=0): t1 = t9[b] scalar; colcoef computed during staging;
// cost[b] += rs[n] * sum_m cc[m]*sqrt(d2). Unscaled coords.
__global__ __launch_bounds__(BLOCK, 4) void emd_C9_kernel(
    const float* __restrict__ xyz1, const float* __restrict__ xyz2,
    const float* __restrict__ rowscale, const float* __restrict__ remainR,
    const float* __restrict__ t9, float* __restrict__ out) {
  __shared__ float4 sP[MPTS];
  __shared__ float sRed[ROWS * 4];
  __shared__ float sCost[ROWS];

  const int tid = threadIdx.x;
  const int bid = blockIdx.x;
  const int b = bid >> 7;
  const int t0 = (bid & 127) * ROWS;
  const int wave = tid >> 6, lane = tid & 63;
  const float t1 = t9[b];

  const float4* q2 = (const float4*)(xyz2 + (size_t)b * MPTS * 3);
  const float4* rr4 = (const float4*)(remainR + (size_t)b * MPTS);
  for (int g = tid; g < MPTS / 4; g += BLOCK) {
    float4 a = q2[3 * g], bb = q2[3 * g + 1], c = q2[3 * g + 2];
    float4 rr = rr4[g];
    float w0 = rr.x * fminf(rr.x / (rr.x * t1 + 1e-9f), 1.0f);
    float w1 = rr.y * fminf(rr.y / (rr.y * t1 + 1e-9f), 1.0f);
    float w2 = rr.z * fminf(rr.z / (rr.z * t1 + 1e-9f), 1.0f);
    float w3 = rr.w * fminf(rr.w / (rr.w * t1 + 1e-9f), 1.0f);
    sP[4 * g + 0] = make_float4(a.x, a.y, a.z, w0);
    sP[4 * g + 1] = make_float4(a.w, bb.x, bb.y, w1);
    sP[4 * g + 2] = make_float4(bb.z, bb.w, c.x, w2);
    sP[4 * g + 3] = make_float4(c.y, c.z, c.w, w3);
  }
  __syncthreads();

  const int phase = lane >> 1, rg = lane & 1;
  const int r0 = t0 + rg * 8;
  float x1[8], y1[8], z1[8], acc[8];
  load8((const float4*)(xyz1 + (size_t)b * NPTS * 3), r0, 1.0f, x1, y1, z1);
#pragma unroll
  for (int j = 0; j < 8; ++j) acc[j] = 0.0f;
  const int mb = wave * 512 + phase;
#pragma unroll 2
  for (int it = 0; it < 16; ++it) {
    float4 v = sP[mb + it * 32];
#pragma unroll
    for (int j = 0; j < 8; ++j) {
      float dx = x1[j] - v.x, dy = y1[j] - v.y, dz = z1[j] - v.z;
      float d2 = __builtin_fmaf(dx, dx, __builtin_fmaf(dy, dy, dz * dz));
      acc[j] = __builtin_fmaf(fast_sqrt(d2), v.w, acc[j]);
    }
  }
#pragma unroll
  for (int j = 0; j < 8; ++j) {
    acc[j] += __shfl_xor(acc[j], 2, 64);
    acc[j] += __shfl_xor(acc[j], 4, 64);
    acc[j] += __shfl_xor(acc[j], 8, 64);
    acc[j] += __shfl_xor(acc[j], 16, 64);
    acc[j] += __shfl_xor(acc[j], 32, 64);
  }
  if (lane < 2) {
#pragma unroll
    for (int j = 0; j < 8; ++j) sRed[(rg * 8 + j) * 4 + wave] = acc[j];
  }
  __syncthreads();
  if (tid < ROWS) {
    float C = sRed[tid * 4] + sRed[tid * 4 + 1] + sRed[tid * 4 + 2] +
              sRed[tid * 4 + 3];
    sCost[tid] = rowscale[(size_t)b * NPTS + t0 + tid] * C;
  }
  __syncthreads();
  if (tid == 0) {
    float t = 0.0f;
#pragma unroll
    for (int i = 0; i < ROWS; ++i) t += sCost[i];
    atomicAdd(out + b, t);
  }
}

// ---------------------------------------------------------------------------
extern "C" void kernel_launch(void* const* d_in, const int* in_sizes, int n_in,
                              void* d_out, int out_size, void* d_ws, size_t ws_size,
                              hipStream_t stream) {
  const float* xyz1 = (const float*)d_in[0];
  const float* xyz2 = (const float*)d_in[1];
  float* out = (float*)d_out;
  float* ws = (float*)d_ws;

  const int BN = BATCH * NPTS, BM = BATCH * MPTS;
  float* remainL  = ws;                  // BN
  float* rowscale = ws + BN;             // BN
  float* rrA      = ws + 2 * BN;         // BM
  float* rrB      = ws + 2 * BN + BM;    // BM
  float* t1b      = ws + 2 * BN + 2 * BM; // 3*BM (buf k = t1b + k*BM)
  float* t9       = ws + 2 * BN + 5 * BM; // BATCH

  const float levels[9] = {-16384.f, -4096.f, -1024.f, -256.f, -64.f,
                           -16.f,    -4.f,    -1.f,    -0.25f};
  dim3 grid(BATCH * (NPTS / ROWS));  // 1024 blocks

  // zero t1 buf0 (A0's accumulation target)
  hipMemsetAsync(t1b, 0, (size_t)BM * sizeof(float), stream);

  emd_A0_kernel<<<grid, BLOCK, 0, stream>>>(
      xyz1, xyz2, rowscale, out, t9, t1b /*acc=buf0*/, t1b + BM /*zero=buf1*/,
      sqrtf(-levels[0] * LOG2E));

  for (int l = 0; l < 9; ++l) {
    float kB = sqrtf(-levels[l] * LOG2E);
    float kA = 0.5f * kB;
    float* cur = t1b + (size_t)(l % 3) * BM;
    float* nxt = t1b + (size_t)((l + 1) % 3) * BM;
    float* zer = t1b + (size_t)((l + 2) % 3) * BM;
    float* rin = (l % 2 == 0) ? rrA : rrB;   // unused for l==0
    float* rou = (l % 2 == 0) ? rrB : rrA;
    if (l == 0) {
      emd_CA_kernel<true, false><<<grid, BLOCK, 0, stream>>>(
          xyz1, xyz2, rowscale, remainL, rin, rou, cur, nxt, zer, out, t9,
          kA, 1.0f / kA);
    } else if (l < 8) {
      emd_CA_kernel<false, false><<<grid, BLOCK, 0, stream>>>(
          xyz1, xyz2, rowscale, remainL, rin, rou, cur, nxt, zer, out, t9,
          kA, 1.0f / kA);
    } else {
      emd_CA_kernel<false, true><<<grid, BLOCK, 0, stream>>>(
          xyz1, xyz2, rowscale, remainL, rin, rou, cur, nxt, zer, out, t9,
          kB, 1.0f / kB);
    }
  }
  // rr_9 was written to rrB (l=8 even). t1_9 scalar in t9.
  emd_C9_kernel<<<grid, BLOCK, 0, stream>>>(xyz1, xyz2, rowscale, rrB, t9, out);
}